// Round 3
// baseline (620.531 us; speedup 1.0000x reference)
//
#include <hip/hip_runtime.h>
#include <math.h>

// QuaternionAttention B=4, L=S=2048, H=8, E=64, M=4 (fp32 in/out).
// Round 11: two-phase precompute. Round-10 (308us) showed VALUBusy 42% /
// MfmaUtil 14% -- the per-tile K_rot build (~200 VALU + 8 sincos per thread
// per tile) was recomputed 32x redundantly across the query-blocks of each
// (b,h). Now: qprep writes K_rot fp16 (33.5MB) + V^T fp16 (8.4MB) into the
// workspace ONCE, already in the swizzled LDS-image layout; the main kernel
// qattn4 stages each tile with 10 coalesced uint4 loads + 10 conflict-free
// LDS writes (issue-early T14 pipeline, same topology as round 10). LDS
// 48KB -> 3 blocks/CU; XCD-chunked block swizzle keeps the 32 blocks of one
// (b,h) on one XCD so K_rot re-reads hit its L2 (3x1.25MB resident < 4MB).
// Falls back to the round-10 kernel if ws_size < 40MB.

#define B_ 4
#define L_ 2048
#define S_ 2048
#define H_ 8
#define E_ 64
#define M_ 4
#define NTH 256
#define NTS (S_ / 64)                       // 32 key tiles
#define KR_TILE_ELEMS (64 * 256)            // f16 per K_rot tile (32KB)
#define VT_TILE_ELEMS (64 * 64)             // f16 per V^T tile (8KB)
#define KR_BYTES ((size_t)B_ * H_ * NTS * KR_TILE_ELEMS * 2)   // 33554432
#define VT_BYTES ((size_t)B_ * H_ * NTS * VT_TILE_ELEMS * 2)   // 8388608

typedef _Float16 f16x4 __attribute__((ext_vector_type(4)));
typedef _Float16 f16x8 __attribute__((ext_vector_type(8)));
typedef __fp16 fp16x2 __attribute__((ext_vector_type(2)));   // cvt_pkrtz return type
typedef float f32x4 __attribute__((ext_vector_type(4)));

union H4U { f16x4 h; fp16x2 p[2]; };
union H8U { f16x8 h; fp16x2 p[4]; };
union F4U { float4 v; float f[4]; };

__device__ __forceinline__ f16x4 cvt4(float x, float y, float z, float w) {
    H4U r;
    r.p[0] = __builtin_amdgcn_cvt_pkrtz(x, y);
    r.p[1] = __builtin_amdgcn_cvt_pkrtz(z, w);
    return r.h;
}
__device__ __forceinline__ f16x8 cvt8(const float* v) {
    H8U r;
#pragma unroll
    for (int i = 0; i < 4; ++i) r.p[i] = __builtin_amdgcn_cvt_pkrtz(v[2 * i], v[2 * i + 1]);
    return r.h;
}

// ============================ prep kernel ============================
// One block per (b,h,stile): builds K_rot + V^T fp16 tiles in the swizzled
// LDS-image layout. Same arithmetic as round-10's in-loop build.
__global__ __launch_bounds__(NTH)
void qprep(const float* __restrict__ kp, const float* __restrict__ vp,
           const float* __restrict__ ko, const float* __restrict__ ktt,
           _Float16* __restrict__ krws, _Float16* __restrict__ vtws)
{
    const int bid = blockIdx.x;             // st + 32*h + 256*b == tile_id
    const int st = bid & 31;
    const int h  = (bid >> 5) & 7;
    const int b  = bid >> 8;
    const int s0 = st * 64;
    const int t  = threadIdx.x;

    const int key_r = t >> 2;
    const int cc    = t & 3;
    const int swz   = key_r & 7;
    const int kg = t >> 4;
    const int eg = t & 15;

    const float* kb0 = kp  + ((size_t)((b * S_) * H_ + h)) * E_;
    const float* vb0 = vp  + ((size_t)((b * S_) * H_ + h)) * E_;
    const float* kob = ko  + ((size_t)((b * S_) * H_ + h)) * M_;
    const float* ktb = ktt + ((size_t)((b * S_) * H_ + h)) * M_;

    F4U kA[4], kB[4], omR, thR, vv[4];
    {
        const float* kr = kb0 + (size_t)(s0 + key_r) * (H_ * E_);
#pragma unroll
        for (int j = 0; j < 4; ++j) {
            kA[j].v = *(const float4*)(kr + cc * 16 + j * 4);        // a = k[cc]
            kB[j].v = *(const float4*)(kr + (cc ^ 2) * 16 + j * 4);  // b = k[cc^2]
        }
        omR.v = *(const float4*)(kob + (size_t)(s0 + key_r) * (H_ * M_));
        thR.v = *(const float4*)(ktb + (size_t)(s0 + key_r) * (H_ * M_));
#pragma unroll
        for (int j = 0; j < 4; ++j)
            vv[j].v = *(const float4*)(vb0 + (size_t)(s0 + kg * 4 + j) * (H_ * E_) + eg * 4);
    }

    _Float16* krt = krws + (size_t)bid * KR_TILE_ELEMS;
    _Float16* vtt = vtws + (size_t)bid * VT_TILE_ELEMS;

    // ---- K_rot (K signs: c0:-, c1:-, c2:+, c3:+) ----
    {
        float af[16], bf[16];
#pragma unroll
        for (int j = 0; j < 4; ++j)
#pragma unroll
            for (int i2 = 0; i2 < 4; ++i2) {
                af[j * 4 + i2] = kA[j].f[i2];
                bf[j * 4 + i2] = kB[j].f[i2];
            }
        float posk = (float)(s0 + key_r) * (1.0f / S_);
        float kcv[4], ksv[4];
#pragma unroll
        for (int m = 0; m < 4; ++m) {
            float ang = omR.f[m] * posk + thR.f[m];
            __sincosf(ang, &ksv[m], &kcv[m]);
        }
        const float sgn = (cc >= 2) ? 1.f : -1.f;
#pragma unroll
        for (int m = 0; m < 4; ++m) {
            float cm = kcv[m], sm = ksv[m] * sgn;
            float vals[16];
#pragma unroll
            for (int i = 0; i < 16; ++i)
                vals[i] = fmaf(bf[i], sm, af[i] * cm);
            int ch0 = (m * 8) | ((cc * 2 + 0) ^ swz);
            int ch1 = (m * 8) | ((cc * 2 + 1) ^ swz);
            *(f16x8*)&krt[key_r * 256 + ch0 * 8] = cvt8(&vals[0]);
            *(f16x8*)&krt[key_r * 256 + ch1 * 8] = cvt8(&vals[8]);
        }
    }
    // ---- V^T (4x4 register-block transpose) ----
    {
#pragma unroll
        for (int e = 0; e < 4; ++e) {
            int row = eg * 4 + e;
            int ch = ((kg >> 1) ^ (row & 7));
            *(f16x4*)&vtt[row * 64 + ch * 8 + (kg & 1) * 4] =
                cvt4(vv[0].f[e], vv[1].f[e], vv[2].f[e], vv[3].f[e]);
        }
    }
}

// ============================ main kernel ============================
__global__ __launch_bounds__(NTH)
void qattn4(const float* __restrict__ qp,
            const float* __restrict__ qo, const float* __restrict__ qt,
            const _Float16* __restrict__ krws, const _Float16* __restrict__ vtws,
            float* __restrict__ out)
{
    // XCD-chunked swizzle: blocks of one (b,h) land on one XCD.
    const int bid0 = blockIdx.x;                 // 0..1023
    const int nl = (bid0 & 7) * 128 + (bid0 >> 3);
    const int l0 = (nl & 31) * 64;
    const int h  = (nl >> 5) & 7;
    const int b  = nl >> 8;
    const int t  = threadIdx.x;
    const int wv   = t >> 6;
    const int lane = t & 63;
    const int quad = lane >> 4;
    const int nn   = lane & 15;

    __shared__ __align__(16) unsigned char smem[49152];
    _Float16 (*krot)[256] = reinterpret_cast<_Float16 (*)[256]>(smem);          // 32KB
    _Float16 (*vts)[64]   = reinterpret_cast<_Float16 (*)[64]>(smem + 32768);   // 8KB
    _Float16 (*pss)[64]   = reinterpret_cast<_Float16 (*)[64]>(smem + 40960);   // 8KB
    float (*qtrc)[4] = reinterpret_cast<float (*)[4]>(smem + 40960);            // overlay pss
    float (*qtrs)[4] = reinterpret_cast<float (*)[4]>(smem + 40960 + 1024);
    float (*qstage)[68] = reinterpret_cast<float (*)[68]>(smem);                // overlay krot

    const _Float16* krbase = krws + (size_t)((b * H_ + h) * NTS) * KR_TILE_ELEMS;
    const _Float16* vtbase = vtws + (size_t)((b * H_ + h) * NTS) * VT_TILE_ELEMS;

    // ---- register staging pipeline (issue-early, write at loop top) ----
    uint4 stg[10];
    auto LOADR = [&](int st) {
        const uint4* kg = (const uint4*)(krbase + (size_t)st * KR_TILE_ELEMS);
        const uint4* vg = (const uint4*)(vtbase + (size_t)st * VT_TILE_ELEMS);
#pragma unroll
        for (int i = 0; i < 8; ++i) stg[i] = kg[i * 256 + t];
        stg[8] = vg[t];
        stg[9] = vg[256 + t];
    };
    LOADR(0);   // tile-0 loads fly under Q_rot construction

    // ---- build Q_rot A-fragments once per block (scale log2(e)/32 folded) ----
    f16x8 qa[8];
    {
        const float* qb = qp + ((size_t)((b * L_ + l0) * H_ + h)) * E_;
#pragma unroll
        for (int i = 0; i < 4; ++i) {
            int idx = t + NTH * i;
            int row = idx >> 4, c16 = idx & 15;
            *(float4*)&qstage[row][c16 * 4] =
                *(const float4*)(qb + (size_t)row * (H_ * E_) + c16 * 4);
        }
        {
            int row = t >> 2, m = t & 3;
            size_t off = (size_t)((b * L_ + l0 + row) * H_ + h) * M_ + m;
            float ang = qo[off] * ((float)(l0 + row) * (1.0f / L_)) + qt[off];
            float sv, cv;
            __sincosf(ang, &sv, &cv);
            qtrc[row][m] = cv;
            qtrs[row][m] = sv;
        }
        __syncthreads();
        const int row = wv * 16 + nn;   // A-frag row = lane&15
        const int i0 = (quad & 1) * 8;
        float sl0[8], sl1[8], sl2[8], sl3[8];
        *(float4*)&sl0[0] = *(float4*)&qstage[row][ 0 + i0];
        *(float4*)&sl0[4] = *(float4*)&qstage[row][ 4 + i0];
        *(float4*)&sl1[0] = *(float4*)&qstage[row][16 + i0];
        *(float4*)&sl1[4] = *(float4*)&qstage[row][20 + i0];
        *(float4*)&sl2[0] = *(float4*)&qstage[row][32 + i0];
        *(float4*)&sl2[4] = *(float4*)&qstage[row][36 + i0];
        *(float4*)&sl3[0] = *(float4*)&qstage[row][48 + i0];
        *(float4*)&sl3[4] = *(float4*)&qstage[row][52 + i0];
        const bool hiC = (quad & 2) != 0;
        float aE[8], bE[8], aO[8], bO[8];
#pragma unroll
        for (int j = 0; j < 8; ++j) {
            aE[j] = hiC ? sl1[j] : sl0[j];
            bE[j] = hiC ? sl0[j] : sl1[j];
            aO[j] = hiC ? sl3[j] : sl2[j];
            bO[j] = hiC ? sl2[j] : sl3[j];
        }
        F4U qc4, qs4;
        qc4.v = *(float4*)&qtrc[row][0];
        qs4.v = *(float4*)&qtrs[row][0];
        const float SC = 0.04508422017f;   // log2(e)/32
#pragma unroll
        for (int m = 0; m < 4; ++m) {
            float cm = qc4.f[m] * SC;
            float sm = qs4.f[m] * SC;
            float sE = hiC ? sm : -sm;     // Q signs: c0:-, c1:+, c2:+, c3:-
            float vE[8], vO[8];
#pragma unroll
            for (int j = 0; j < 8; ++j) {
                vE[j] = fmaf(bE[j], sE, aE[j] * cm);
                vO[j] = fmaf(bO[j], -sE, aO[j] * cm);
            }
            qa[2 * m]     = cvt8(vE);
            qa[2 * m + 1] = cvt8(vO);
        }
        __syncthreads();   // qstage/qtr overlays now free
    }

    f32x4 Oacc[4] = {{0,0,0,0},{0,0,0,0},{0,0,0,0},{0,0,0,0}};
    float mrow[4] = {-1e30f,-1e30f,-1e30f,-1e30f};
    float lrow[4] = {0.f,0.f,0.f,0.f};
    const int xr0 = nn & 7;

    uint4* kl = (uint4*)&krot[0][0];
    uint4* vl = (uint4*)&vts[0][0];

    for (int st = 0; st < NTS; ++st) {
        // ---- LDS staging from pipeline regs (conflict-free: consecutive chunks) ----
#pragma unroll
        for (int i = 0; i < 8; ++i) kl[i * 256 + t] = stg[i];
        vl[t]       = stg[8];
        vl[256 + t] = stg[9];
        if (st + 1 < NTS) LOADR(st + 1);   // next tile in flight across compute
        __syncthreads();

        // ---- QK^T: one K=256 MFMA chain, scores come out pre-scaled ----
        float sc[4][4];
#pragma unroll
        for (int kt2 = 0; kt2 < 4; ++kt2) {
            const int keyb = kt2 * 16 + nn;
            f32x4 acc = {0, 0, 0, 0};
#pragma unroll
            for (int ks = 0; ks < 8; ++ks) {
                f16x8 bK = *(const f16x8*)&krot[keyb][((ks * 4 + quad) ^ xr0) * 8];
                acc = __builtin_amdgcn_mfma_f32_16x16x32_f16(qa[ks], bK, acc, 0, 0, 0);
            }
#pragma unroll
            for (int r = 0; r < 4; ++r) sc[kt2][r] = acc[r];
        }

        // ---- online softmax in base 2, P write (bit3-fixed swizzle) ----
#pragma unroll
        for (int r = 0; r < 4; ++r) {
            float tm = fmaxf(fmaxf(sc[0][r], sc[1][r]), fmaxf(sc[2][r], sc[3][r]));
            tm = fmaxf(tm, __shfl_xor(tm, 1));
            tm = fmaxf(tm, __shfl_xor(tm, 2));
            tm = fmaxf(tm, __shfl_xor(tm, 4));
            tm = fmaxf(tm, __shfl_xor(tm, 8));
            float mnew  = fmaxf(mrow[r], tm);
            float alpha = __builtin_amdgcn_exp2f(mrow[r] - mnew);
            int row = wv * 16 + quad * 4 + r;
            int sw = (row & 7) ^ ((row >> 3) & 1);
            float psum = 0.f;
#pragma unroll
            for (int kt2 = 0; kt2 < 4; ++kt2) {
                float p = __builtin_amdgcn_exp2f(sc[kt2][r] - mnew);
                psum += p;
                int key = kt2 * 16 + nn;
                int ch = (key >> 3) ^ sw;
                pss[row][ch * 8 + (key & 7)] = (_Float16)p;
            }
            psum += __shfl_xor(psum, 1);
            psum += __shfl_xor(psum, 2);
            psum += __shfl_xor(psum, 4);
            psum += __shfl_xor(psum, 8);
            lrow[r] = lrow[r] * alpha + psum;
            mrow[r] = mnew;
            Oacc[0][r] *= alpha; Oacc[1][r] *= alpha;
            Oacc[2][r] *= alpha; Oacc[3][r] *= alpha;
        }

        // ---- PV (wave-local P round-trip, no barrier needed) ----
        {
            const int prow = wv * 16 + nn;
            const int swp = (prow & 7) ^ ((prow >> 3) & 1);
#pragma unroll
            for (int ks2 = 0; ks2 < 2; ++ks2) {
                f16x8 pf = *(const f16x8*)&pss[prow][((quad + 4 * ks2) ^ swp) * 8];
#pragma unroll
                for (int et = 0; et < 4; ++et) {
                    int e = et * 16 + nn;
                    f16x8 vf = *(const f16x8*)&vts[e][((quad + 4 * ks2) ^ (e & 7)) * 8];
                    Oacc[et] = __builtin_amdgcn_mfma_f32_16x16x32_f16(pf, vf, Oacc[et], 0, 0, 0);
                }
            }
        }
        __syncthreads();   // all krot/vts reads done before next staging writes
    }

    // ---- epilogue ----
    float* ob = out + ((size_t)((b * L_ + l0) * H_ + h)) * E_;
#pragma unroll
    for (int r = 0; r < 4; ++r) {
        float inv = 1.0f / lrow[r];
        int row = wv * 16 + quad * 4 + r;
#pragma unroll
        for (int et = 0; et < 4; ++et)
            ob[(size_t)row * (H_ * E_) + et * 16 + nn] = Oacc[et][r] * inv;
    }
}

// ============================ fallback (round-10 kernel, passing at 308us) ============================
__global__ __launch_bounds__(NTH)
void qattn3(const float* __restrict__ qp, const float* __restrict__ kp,
            const float* __restrict__ vp,
            const float* __restrict__ qo, const float* __restrict__ qt,
            const float* __restrict__ ko, const float* __restrict__ ktt,
            float* __restrict__ out)
{
    const int l0 = blockIdx.x * 64;
    const int h  = blockIdx.y;
    const int b  = blockIdx.z;
    const int t  = threadIdx.x;
    const int wv   = t >> 6;
    const int lane = t & 63;
    const int quad = lane >> 4;
    const int nn   = lane & 15;

    __shared__ __align__(16) _Float16 krot[64][256];
    __shared__ __align__(16) _Float16 vts[64][64];
    __shared__ __align__(16) _Float16 pss[64][64];
    __shared__ float qtrc[64][4], qtrs[64][4];

    const float* kb0 = kp  + ((size_t)((b * S_) * H_ + h)) * E_;
    const float* vb0 = vp  + ((size_t)((b * S_) * H_ + h)) * E_;
    const float* kob = ko  + ((size_t)((b * S_) * H_ + h)) * M_;
    const float* ktb = ktt + ((size_t)((b * S_) * H_ + h)) * M_;

    const int key_r = t >> 2;
    const int cc    = t & 3;
    const int swz   = key_r & 7;
    const int kg = t >> 4;
    const int eg = t & 15;

    F4U kA[4], kB[4], omR, thR, vv[4];
    auto LOAD = [&](int s0) {
        const float* kr = kb0 + (size_t)(s0 + key_r) * (H_ * E_);
#pragma unroll
        for (int j = 0; j < 4; ++j) {
            kA[j].v = *(const float4*)(kr + cc * 16 + j * 4);
            kB[j].v = *(const float4*)(kr + (cc ^ 2) * 16 + j * 4);
        }
        omR.v = *(const float4*)(kob + (size_t)(s0 + key_r) * (H_ * M_));
        thR.v = *(const float4*)(ktb + (size_t)(s0 + key_r) * (H_ * M_));
#pragma unroll
        for (int j = 0; j < 4; ++j)
            vv[j].v = *(const float4*)(vb0 + (size_t)(s0 + kg * 4 + j) * (H_ * E_) + eg * 4);
    };
    LOAD(0);

    f16x8 qa[8];
    {
        float (*qstage)[68] = reinterpret_cast<float (*)[68]>(&krot[0][0]);
        const float* qb = qp + ((size_t)((b * L_ + l0) * H_ + h)) * E_;
#pragma unroll
        for (int i = 0; i < 4; ++i) {
            int idx = t + NTH * i;
            int row = idx >> 4, c16 = idx & 15;
            *(float4*)&qstage[row][c16 * 4] =
                *(const float4*)(qb + (size_t)row * (H_ * E_) + c16 * 4);
        }
        {
            int row = t >> 2, m = t & 3;
            size_t off = (size_t)((b * L_ + l0 + row) * H_ + h) * M_ + m;
            float ang = qo[off] * ((float)(l0 + row) * (1.0f / L_)) + qt[off];
            float sv, cv;
            __sincosf(ang, &sv, &cv);
            qtrc[row][m] = cv;
            qtrs[row][m] = sv;
        }
        __syncthreads();
        const int row = wv * 16 + nn;
        const int i0 = (quad & 1) * 8;
        float sl0[8], sl1[8], sl2[8], sl3[8];
        *(float4*)&sl0[0] = *(float4*)&qstage[row][ 0 + i0];
        *(float4*)&sl0[4] = *(float4*)&qstage[row][ 4 + i0];
        *(float4*)&sl1[0] = *(float4*)&qstage[row][16 + i0];
        *(float4*)&sl1[4] = *(float4*)&qstage[row][20 + i0];
        *(float4*)&sl2[0] = *(float4*)&qstage[row][32 + i0];
        *(float4*)&sl2[4] = *(float4*)&qstage[row][36 + i0];
        *(float4*)&sl3[0] = *(float4*)&qstage[row][48 + i0];
        *(float4*)&sl3[4] = *(float4*)&qstage[row][52 + i0];
        const bool hiC = (quad & 2) != 0;
        float aE[8], bE[8], aO[8], bO[8];
#pragma unroll
        for (int j = 0; j < 8; ++j) {
            aE[j] = hiC ? sl1[j] : sl0[j];
            bE[j] = hiC ? sl0[j] : sl1[j];
            aO[j] = hiC ? sl3[j] : sl2[j];
            bO[j] = hiC ? sl2[j] : sl3[j];
        }
        F4U qc4, qs4;
        qc4.v = *(float4*)&qtrc[row][0];
        qs4.v = *(float4*)&qtrs[row][0];
        const float SC = 0.04508422017f;
#pragma unroll
        for (int m = 0; m < 4; ++m) {
            float cm = qc4.f[m] * SC;
            float sm = qs4.f[m] * SC;
            float sE = hiC ? sm : -sm;
            float vE[8], vO[8];
#pragma unroll
            for (int j = 0; j < 8; ++j) {
                vE[j] = fmaf(bE[j], sE, aE[j] * cm);
                vO[j] = fmaf(bO[j], -sE, aO[j] * cm);
            }
            qa[2 * m]     = cvt8(vE);
            qa[2 * m + 1] = cvt8(vO);
        }
        __syncthreads();
    }

    f32x4 Oacc[4] = {{0,0,0,0},{0,0,0,0},{0,0,0,0},{0,0,0,0}};
    float mrow[4] = {-1e30f,-1e30f,-1e30f,-1e30f};
    float lrow[4] = {0.f,0.f,0.f,0.f};
    const int xr0 = nn & 7;

    for (int s0 = 0; s0 < S_; s0 += 64) {
        {
            float af[16], bf[16];
#pragma unroll
            for (int j = 0; j < 4; ++j)
#pragma unroll
                for (int i2 = 0; i2 < 4; ++i2) {
                    af[j * 4 + i2] = kA[j].f[i2];
                    bf[j * 4 + i2] = kB[j].f[i2];
                }
            float posk = (float)(s0 + key_r) * (1.0f / S_);
            float kcv[4], ksv[4];
#pragma unroll
            for (int m = 0; m < 4; ++m) {
                float ang = omR.f[m] * posk + thR.f[m];
                __sincosf(ang, &ksv[m], &kcv[m]);
            }
            const float sgn = (cc >= 2) ? 1.f : -1.f;
#pragma unroll
            for (int m = 0; m < 4; ++m) {
                float cm = kcv[m], sm = ksv[m] * sgn;
                float vals[16];
#pragma unroll
                for (int i = 0; i < 16; ++i)
                    vals[i] = fmaf(bf[i], sm, af[i] * cm);
                int ch0 = (m * 8) | ((cc * 2 + 0) ^ swz);
                int ch1 = (m * 8) | ((cc * 2 + 1) ^ swz);
                *(f16x8*)&krot[key_r][ch0 * 8] = cvt8(&vals[0]);
                *(f16x8*)&krot[key_r][ch1 * 8] = cvt8(&vals[8]);
            }
        }
        {
#pragma unroll
            for (int e = 0; e < 4; ++e) {
                int row = eg * 4 + e;
                int ch = ((kg >> 1) ^ (row & 7));
                *(f16x4*)&vts[row][ch * 8 + (kg & 1) * 4] =
                    cvt4(vv[0].f[e], vv[1].f[e], vv[2].f[e], vv[3].f[e]);
            }
        }
        if (s0 + 64 < S_) LOAD(s0 + 64);
        __syncthreads();

        float sc[4][4];
#pragma unroll
        for (int kt2 = 0; kt2 < 4; ++kt2) {
            const int keyb = kt2 * 16 + nn;
            f32x4 acc = {0, 0, 0, 0};
#pragma unroll
            for (int ks = 0; ks < 8; ++ks) {
                f16x8 bK = *(const f16x8*)&krot[keyb][((ks * 4 + quad) ^ xr0) * 8];
                acc = __builtin_amdgcn_mfma_f32_16x16x32_f16(qa[ks], bK, acc, 0, 0, 0);
            }
#pragma unroll
            for (int r = 0; r < 4; ++r) sc[kt2][r] = acc[r];
        }

#pragma unroll
        for (int r = 0; r < 4; ++r) {
            float tm = fmaxf(fmaxf(sc[0][r], sc[1][r]), fmaxf(sc[2][r], sc[3][r]));
            tm = fmaxf(tm, __shfl_xor(tm, 1));
            tm = fmaxf(tm, __shfl_xor(tm, 2));
            tm = fmaxf(tm, __shfl_xor(tm, 4));
            tm = fmaxf(tm, __shfl_xor(tm, 8));
            float mnew  = fmaxf(mrow[r], tm);
            float alpha = __builtin_amdgcn_exp2f(mrow[r] - mnew);
            int row = wv * 16 + quad * 4 + r;
            int sw = (row & 7) ^ ((row >> 3) & 1);
            float psum = 0.f;
#pragma unroll
            for (int kt2 = 0; kt2 < 4; ++kt2) {
                float p = __builtin_amdgcn_exp2f(sc[kt2][r] - mnew);
                psum += p;
                int key = kt2 * 16 + nn;
                int ch = (key >> 3) ^ sw;
                pss[row][ch * 8 + (key & 7)] = (_Float16)p;
            }
            psum += __shfl_xor(psum, 1);
            psum += __shfl_xor(psum, 2);
            psum += __shfl_xor(psum, 4);
            psum += __shfl_xor(psum, 8);
            lrow[r] = lrow[r] * alpha + psum;
            mrow[r] = mnew;
            Oacc[0][r] *= alpha; Oacc[1][r] *= alpha;
            Oacc[2][r] *= alpha; Oacc[3][r] *= alpha;
        }

        {
            const int prow = wv * 16 + nn;
            const int swp = (prow & 7) ^ ((prow >> 3) & 1);
#pragma unroll
            for (int ks2 = 0; ks2 < 2; ++ks2) {
                f16x8 pf = *(const f16x8*)&pss[prow][((quad + 4 * ks2) ^ swp) * 8];
#pragma unroll
                for (int et = 0; et < 4; ++et) {
                    int e = et * 16 + nn;
                    f16x8 vf = *(const f16x8*)&vts[e][((quad + 4 * ks2) ^ (e & 7)) * 8];
                    Oacc[et] = __builtin_amdgcn_mfma_f32_16x16x32_f16(pf, vf, Oacc[et], 0, 0, 0);
                }
            }
        }
        __syncthreads();
    }

    float* ob = out + ((size_t)((b * L_ + l0) * H_ + h)) * E_;
#pragma unroll
    for (int r = 0; r < 4; ++r) {
        float inv = 1.0f / lrow[r];
        int row = wv * 16 + quad * 4 + r;
#pragma unroll
        for (int et = 0; et < 4; ++et)
            ob[(size_t)row * (H_ * E_) + et * 16 + nn] = Oacc[et][r] * inv;
    }
}

extern "C" void kernel_launch(void* const* d_in, const int* in_sizes, int n_in,
                              void* d_out, int out_size, void* d_ws, size_t ws_size,
                              hipStream_t stream) {
    const float* qp = (const float*)d_in[0];
    const float* kp = (const float*)d_in[1];
    const float* vp = (const float*)d_in[2];
    const float* qo = (const float*)d_in[3];
    const float* qt = (const float*)d_in[4];
    const float* ko = (const float*)d_in[5];
    const float* kt = (const float*)d_in[6];
    float* out = (float*)d_out;

    const size_t need = KR_BYTES + VT_BYTES;   // 40MB
    if (d_ws != nullptr && ws_size >= need) {
        _Float16* krws = (_Float16*)d_ws;
        _Float16* vtws = (_Float16*)((char*)d_ws + KR_BYTES);
        qprep<<<dim3(B_ * H_ * NTS), dim3(NTH), 0, stream>>>(kp, vp, ko, kt, krws, vtws);
        qattn4<<<dim3(B_ * H_ * (L_ / 64)), dim3(NTH), 0, stream>>>(qp, qo, qt, krws, vtws, out);
    } else {
        dim3 grid(L_ / 64, H_, B_);
        qattn3<<<grid, dim3(NTH), 0, stream>>>(qp, kp, vp, qo, qt, ko, kt, out);
    }
}

// Round 4
// 281.986 us; speedup vs baseline: 2.2006x; 2.2006x over previous
//
#include <hip/hip_runtime.h>
#include <math.h>

// QuaternionAttention B=4, L=S=2048, H=8, E=64, M=4 (fp32 in/out).
// Round 12: QBLK=128 / NTH=512 amortization of the K_rot rebuild.
// Round-11's workspace precompute was 2.2x WORSE (573us, LLC-stream-bound at
// 2.2TB/s) -> recompute beats materialize; reverted to round-10 structure.
// Round-10 (262us): VALUBusy 42% dominated by the per-tile K_rot build
// (~200 VALU/thread), rebuilt 32x per (b,h). Now each block covers 128 query
// rows with 8 waves: rebuild count halves AND the build spreads over 512
// threads (each thread: one e-half of one (key, component) = 2 float4 a/b
// loads, 4m x 8 fma-pairs, 4 f16x8 stores ~= 100 ops). Per-wave QK/softmax/
// P/PV code identical to round-10. LDS 56KB -> 2 blocks/CU, grid 512 = exactly
// 2 blocks/CU (no tail rounds), 16 waves/CU. XCD swizzle keeps the 16 blocks
// of each (b,h) on one XCD (~4 KV sets ~= 4.4MB ~ L2).

#define B_ 4
#define L_ 2048
#define S_ 2048
#define H_ 8
#define E_ 64
#define M_ 4
#define QBLK 128
#define NTH 512

typedef _Float16 f16x4 __attribute__((ext_vector_type(4)));
typedef _Float16 f16x8 __attribute__((ext_vector_type(8)));
typedef __fp16 fp16x2 __attribute__((ext_vector_type(2)));   // cvt_pkrtz return type
typedef float f32x4 __attribute__((ext_vector_type(4)));

union H4U { f16x4 h; fp16x2 p[2]; };
union H8U { f16x8 h; fp16x2 p[4]; };
union F4U { float4 v; float f[4]; };

__device__ __forceinline__ f16x4 cvt4(float x, float y, float z, float w) {
    H4U r;
    r.p[0] = __builtin_amdgcn_cvt_pkrtz(x, y);
    r.p[1] = __builtin_amdgcn_cvt_pkrtz(z, w);
    return r.h;
}
__device__ __forceinline__ f16x8 cvt8(const float* v) {
    H8U r;
#pragma unroll
    for (int i = 0; i < 4; ++i) r.p[i] = __builtin_amdgcn_cvt_pkrtz(v[2 * i], v[2 * i + 1]);
    return r.h;
}

__global__ __launch_bounds__(NTH)
void qattn5(const float* __restrict__ qp, const float* __restrict__ kp,
            const float* __restrict__ vp,
            const float* __restrict__ qo, const float* __restrict__ qt,
            const float* __restrict__ ko, const float* __restrict__ ktt,
            float* __restrict__ out)
{
    // XCD-chunked swizzle (512 = 8 XCD x 64, bijective): consecutive nl
    // (same (b,h)) land on one XCD.
    const int bid0 = blockIdx.x;                  // 0..511
    const int nl = (bid0 & 7) * 64 + (bid0 >> 3);
    const int l0 = (nl & 15) * QBLK;
    const int h  = (nl >> 4) & 7;
    const int b  = nl >> 7;
    const int t  = threadIdx.x;
    const int wv   = t >> 6;                      // 0..7
    const int lane = t & 63;
    const int quad = lane >> 4;
    const int nn   = lane & 15;

    // LDS: krot 32K | vts 8K | pss 16K = 56KB (2 blocks/CU)
    __shared__ __align__(16) unsigned char smem[57344];
    _Float16 (*krot)[256] = reinterpret_cast<_Float16 (*)[256]>(smem);          // 32KB
    _Float16 (*vts)[64]   = reinterpret_cast<_Float16 (*)[64]>(smem + 32768);   // 8KB
    _Float16 (*pss)[64]   = reinterpret_cast<_Float16 (*)[64]>(smem + 40960);   // 16KB
    float (*qtrc)[4] = reinterpret_cast<float (*)[4]>(smem + 40960);            // overlay pss
    float (*qtrs)[4] = reinterpret_cast<float (*)[4]>(smem + 40960 + 2048);
    float (*qstage)[64] = reinterpret_cast<float (*)[64]>(smem);                // overlay krot (32KB)

    const float* kb0 = kp  + ((size_t)((b * S_) * H_ + h)) * E_;
    const float* vb0 = vp  + ((size_t)((b * S_) * H_ + h)) * E_;
    const float* kob = ko  + ((size_t)((b * S_) * H_ + h)) * M_;
    const float* ktb = ktt + ((size_t)((b * S_) * H_ + h)) * M_;

    // K_rot build roles: 8 threads per key = 4 components x 2 e-halves
    const int key_r = t >> 3;       // 0..63
    const int ccr   = (t >> 1) & 3; // component
    const int eh    = t & 1;        // e-half within component
    const int swz   = key_r & 7;
    // V^T roles (upper 256 threads)
    const int tt = t & 255;
    const int kg = tt >> 4;         // key group (4 keys)
    const int eg = tt & 15;         // e group (4 e's)

    // ---- register pipeline: next tile's K slices, trig, V rows ----
    F4U kA[2], kB[2], omR, thR, vv[4];
    auto LOAD = [&](int s0) {
        const float* kr = kb0 + (size_t)(s0 + key_r) * (H_ * E_);
        kA[0].v = *(const float4*)(kr + ccr * 16 + eh * 8);            // a = k[cc]
        kA[1].v = *(const float4*)(kr + ccr * 16 + eh * 8 + 4);
        kB[0].v = *(const float4*)(kr + (ccr ^ 2) * 16 + eh * 8);      // b = k[cc^2]
        kB[1].v = *(const float4*)(kr + (ccr ^ 2) * 16 + eh * 8 + 4);
        omR.v = *(const float4*)(kob + (size_t)(s0 + key_r) * (H_ * M_));
        thR.v = *(const float4*)(ktb + (size_t)(s0 + key_r) * (H_ * M_));
        if (t >= 256) {
#pragma unroll
            for (int j = 0; j < 4; ++j)
                vv[j].v = *(const float4*)(vb0 + (size_t)(s0 + kg * 4 + j) * (H_ * E_) + eg * 4);
        }
    };
    LOAD(0);   // tile-0 loads fly under Q_rot construction

    // ---- build Q_rot A-fragments once per block (scale log2(e)/32 folded) ----
    // A-frag ks (K=32 step): kd = ks*32 + quad*8 + j -> m=ks>>1,
    // c = (ks&1)*2 + (quad>>1), i = (quad&1)*8 + j.
    f16x8 qa[8];
    {
        const float* qb = qp + ((size_t)((b * L_ + l0) * H_ + h)) * E_;
#pragma unroll
        for (int i = 0; i < 4; ++i) {
            int idx = t + NTH * i;                 // 0..2047
            int row = idx >> 4, c16 = idx & 15;
            *(float4*)&qstage[row][c16 * 4] =
                *(const float4*)(qb + (size_t)row * (H_ * E_) + c16 * 4);
        }
        {
            int row = t >> 2, m = t & 3;           // 128 rows x 4 m = 512
            size_t off = (size_t)((b * L_ + l0 + row) * H_ + h) * M_ + m;
            float ang = qo[off] * ((float)(l0 + row) * (1.0f / L_)) + qt[off];
            float sv, cv;
            __sincosf(ang, &sv, &cv);
            qtrc[row][m] = cv;
            qtrs[row][m] = sv;
        }
        __syncthreads();
        const int row = wv * 16 + nn;              // 0..127: A-frag row = lane&15
        const int i0 = (quad & 1) * 8;
        float sl0[8], sl1[8], sl2[8], sl3[8];
        *(float4*)&sl0[0] = *(float4*)&qstage[row][ 0 + i0];
        *(float4*)&sl0[4] = *(float4*)&qstage[row][ 4 + i0];
        *(float4*)&sl1[0] = *(float4*)&qstage[row][16 + i0];
        *(float4*)&sl1[4] = *(float4*)&qstage[row][20 + i0];
        *(float4*)&sl2[0] = *(float4*)&qstage[row][32 + i0];
        *(float4*)&sl2[4] = *(float4*)&qstage[row][36 + i0];
        *(float4*)&sl3[0] = *(float4*)&qstage[row][48 + i0];
        *(float4*)&sl3[4] = *(float4*)&qstage[row][52 + i0];
        // even ks -> c = quad>>1 (0 or 1); odd ks -> c+2.
        // Q signs: c0:-, c1:+, c2:+, c3:-   (b = q[c^1])
        const bool hiC = (quad & 2) != 0;
        float aE[8], bE[8], aO[8], bO[8];
#pragma unroll
        for (int j = 0; j < 8; ++j) {
            aE[j] = hiC ? sl1[j] : sl0[j];
            bE[j] = hiC ? sl0[j] : sl1[j];
            aO[j] = hiC ? sl3[j] : sl2[j];
            bO[j] = hiC ? sl2[j] : sl3[j];
        }
        F4U qc4, qs4;
        qc4.v = *(float4*)&qtrc[row][0];
        qs4.v = *(float4*)&qtrs[row][0];
        const float SC = 0.04508422017f;   // log2(e)/32
#pragma unroll
        for (int m = 0; m < 4; ++m) {
            float cm = qc4.f[m] * SC;
            float sm = qs4.f[m] * SC;
            float sE = hiC ? sm : -sm;     // c=1:+  c=0:-
            float vE[8], vO[8];
#pragma unroll
            for (int j = 0; j < 8; ++j) {
                vE[j] = fmaf(bE[j], sE, aE[j] * cm);
                vO[j] = fmaf(bO[j], -sE, aO[j] * cm);   // c=2:+  c=3:-
            }
            qa[2 * m]     = cvt8(vE);
            qa[2 * m + 1] = cvt8(vO);
        }
        __syncthreads();   // qstage (krot alias) + qtr (pss alias) now free
    }

    f32x4 Oacc[4] = {{0,0,0,0},{0,0,0,0},{0,0,0,0},{0,0,0,0}};
    float mrow[4] = {-1e30f,-1e30f,-1e30f,-1e30f};
    float lrow[4] = {0.f,0.f,0.f,0.f};
    const int xr0 = nn & 7;

    for (int s0 = 0; s0 < S_; s0 += 64) {
        // ---- K_rot build from pipeline regs (K signs: c0:-, c1:-, c2:+, c3:+) ----
        {
            float af[8], bf[8];
#pragma unroll
            for (int i2 = 0; i2 < 4; ++i2) {
                af[i2]     = kA[0].f[i2];
                af[4 + i2] = kA[1].f[i2];
                bf[i2]     = kB[0].f[i2];
                bf[4 + i2] = kB[1].f[i2];
            }
            float posk = (float)(s0 + key_r) * (1.0f / S_);
            float kcv[4], ksv[4];
#pragma unroll
            for (int m = 0; m < 4; ++m) {
                float ang = omR.f[m] * posk + thR.f[m];
                __sincosf(ang, &ksv[m], &kcv[m]);
            }
            const float sgn = (ccr >= 2) ? 1.f : -1.f;
#pragma unroll
            for (int m = 0; m < 4; ++m) {
                float cm = kcv[m], sm = ksv[m] * sgn;
                float vals[8];
#pragma unroll
                for (int i = 0; i < 8; ++i)
                    vals[i] = fmaf(bf[i], sm, af[i] * cm);
                int ch = (m * 8) | ((ccr * 2 + eh) ^ swz);
                *(f16x8*)&krot[key_r][ch * 8] = cvt8(vals);
            }
        }
        // ---- V^T staging (upper 256 threads, 4x4 register-block transpose) ----
        if (t >= 256) {
#pragma unroll
            for (int e = 0; e < 4; ++e) {
                int row = eg * 4 + e;
                int ch = ((kg >> 1) ^ (row & 7));
                *(f16x4*)&vts[row][ch * 8 + (kg & 1) * 4] =
                    cvt4(vv[0].f[e], vv[1].f[e], vv[2].f[e], vv[3].f[e]);
            }
        }
        if (s0 + 64 < S_) LOAD(s0 + 64);   // next tile in flight across compute
        __syncthreads();

        // ---- QK^T: one K=256 MFMA chain, scores come out pre-scaled ----
        float sc[4][4];
#pragma unroll
        for (int kt2 = 0; kt2 < 4; ++kt2) {
            const int keyb = kt2 * 16 + nn;
            f32x4 acc = {0, 0, 0, 0};
#pragma unroll
            for (int ks = 0; ks < 8; ++ks) {
                f16x8 bK = *(const f16x8*)&krot[keyb][((ks * 4 + quad) ^ xr0) * 8];
                acc = __builtin_amdgcn_mfma_f32_16x16x32_f16(qa[ks], bK, acc, 0, 0, 0);
            }
#pragma unroll
            for (int r = 0; r < 4; ++r) sc[kt2][r] = acc[r];
        }

        // ---- online softmax in base 2, P write (bit3-fixed swizzle) ----
#pragma unroll
        for (int r = 0; r < 4; ++r) {
            float tm = fmaxf(fmaxf(sc[0][r], sc[1][r]), fmaxf(sc[2][r], sc[3][r]));
            tm = fmaxf(tm, __shfl_xor(tm, 1));
            tm = fmaxf(tm, __shfl_xor(tm, 2));
            tm = fmaxf(tm, __shfl_xor(tm, 4));
            tm = fmaxf(tm, __shfl_xor(tm, 8));
            float mnew  = fmaxf(mrow[r], tm);
            float alpha = __builtin_amdgcn_exp2f(mrow[r] - mnew);
            int row = wv * 16 + quad * 4 + r;      // 0..127
            int sw = (row & 7) ^ ((row >> 3) & 1);
            float psum = 0.f;
#pragma unroll
            for (int kt2 = 0; kt2 < 4; ++kt2) {
                float p = __builtin_amdgcn_exp2f(sc[kt2][r] - mnew);
                psum += p;
                int key = kt2 * 16 + nn;
                int ch = (key >> 3) ^ sw;
                pss[row][ch * 8 + (key & 7)] = (_Float16)p;
            }
            psum += __shfl_xor(psum, 1);
            psum += __shfl_xor(psum, 2);
            psum += __shfl_xor(psum, 4);
            psum += __shfl_xor(psum, 8);
            lrow[r] = lrow[r] * alpha + psum;
            mrow[r] = mnew;
            Oacc[0][r] *= alpha; Oacc[1][r] *= alpha;
            Oacc[2][r] *= alpha; Oacc[3][r] *= alpha;
        }

        // ---- PV (wave-local P round-trip, no barrier needed) ----
        {
            const int prow = wv * 16 + nn;         // 0..127
            const int swp = (prow & 7) ^ ((prow >> 3) & 1);
#pragma unroll
            for (int ks2 = 0; ks2 < 2; ++ks2) {
                f16x8 pf = *(const f16x8*)&pss[prow][((quad + 4 * ks2) ^ swp) * 8];
#pragma unroll
                for (int et = 0; et < 4; ++et) {
                    int e = et * 16 + nn;
                    f16x8 vf = *(const f16x8*)&vts[e][((quad + 4 * ks2) ^ (e & 7)) * 8];
                    Oacc[et] = __builtin_amdgcn_mfma_f32_16x16x32_f16(pf, vf, Oacc[et], 0, 0, 0);
                }
            }
        }
        __syncthreads();   // all krot/vts/pss reads done before next staging
    }

    // ---- epilogue ----
    float* ob = out + ((size_t)((b * L_ + l0) * H_ + h)) * E_;
#pragma unroll
    for (int r = 0; r < 4; ++r) {
        float inv = 1.0f / lrow[r];
        int row = wv * 16 + quad * 4 + r;          // 0..127
#pragma unroll
        for (int et = 0; et < 4; ++et)
            ob[(size_t)row * (H_ * E_) + et * 16 + nn] = Oacc[et][r] * inv;
    }
}

extern "C" void kernel_launch(void* const* d_in, const int* in_sizes, int n_in,
                              void* d_out, int out_size, void* d_ws, size_t ws_size,
                              hipStream_t stream) {
    const float* qp = (const float*)d_in[0];
    const float* kp = (const float*)d_in[1];
    const float* vp = (const float*)d_in[2];
    const float* qo = (const float*)d_in[3];
    const float* qt = (const float*)d_in[4];
    const float* ko = (const float*)d_in[5];
    const float* kt = (const float*)d_in[6];
    float* out = (float*)d_out;

    qattn5<<<dim3(B_ * H_ * (L_ / QBLK)), dim3(NTH), 0, stream>>>(
        qp, kp, vp, qo, qt, ko, kt, out);
}

// Round 5
// 247.380 us; speedup vs baseline: 2.5084x; 1.1399x over previous
//
#include <hip/hip_runtime.h>
#include <math.h>

// QuaternionAttention B=4, L=S=2048, H=8, E=64, M=4 (fp32 in/out).
// Round 13: swapped-QK lane-local softmax + defer-max, on the round-12 base
// (227us dispatch: QBLK=128/NTH=512, K_rot rebuilt per tile by 512 threads).
//
// Key change: QK^T computed as mfma(K_frag, Q_frag) -- A/B frags have the
// same lane layout (idx=lane&15, k=quad*8+j), so swapping operands
// transposes the score tile for free: lane (quad,nn) now holds 16 keys
// (kt2*16+quad*4+r) for the ONE Q-row nn. Softmax row-reduce = 15 lane-local
// ops + 2 shfl_xor(16/32) instead of 32 shfl pairs; m/l state is scalar;
// P packs to 8 dwords (8 ds_write_b32, was 16 ds_write_b16). PV / V^T /
// K_rot build / staging identical to round 12. Alpha for the O-fragment
// rows (quad*4+r) is shfl-broadcast from lane quad*4+r (all quads hold the
// fully-reduced row values). T13 defer-max (THR=8 base-2): wave-uniform
// skip of alpha+O-rescale when no row max grows; p <= 2^8 is f16-safe with
// unchanged relative precision.

#define B_ 4
#define L_ 2048
#define S_ 2048
#define H_ 8
#define E_ 64
#define M_ 4
#define QBLK 128
#define NTH 512

typedef _Float16 f16x4 __attribute__((ext_vector_type(4)));
typedef _Float16 f16x8 __attribute__((ext_vector_type(8)));
typedef __fp16 fp16x2 __attribute__((ext_vector_type(2)));   // cvt_pkrtz return type
typedef float f32x4 __attribute__((ext_vector_type(4)));

union H4U { f16x4 h; fp16x2 p[2]; };
union H8U { f16x8 h; fp16x2 p[4]; };
union F4U { float4 v; float f[4]; };

__device__ __forceinline__ f16x4 cvt4(float x, float y, float z, float w) {
    H4U r;
    r.p[0] = __builtin_amdgcn_cvt_pkrtz(x, y);
    r.p[1] = __builtin_amdgcn_cvt_pkrtz(z, w);
    return r.h;
}
__device__ __forceinline__ f16x8 cvt8(const float* v) {
    H8U r;
#pragma unroll
    for (int i = 0; i < 4; ++i) r.p[i] = __builtin_amdgcn_cvt_pkrtz(v[2 * i], v[2 * i + 1]);
    return r.h;
}

__global__ __launch_bounds__(NTH)
void qattn6(const float* __restrict__ qp, const float* __restrict__ kp,
            const float* __restrict__ vp,
            const float* __restrict__ qo, const float* __restrict__ qt,
            const float* __restrict__ ko, const float* __restrict__ ktt,
            float* __restrict__ out)
{
    // XCD-chunked swizzle (512 = 8 XCD x 64, bijective): consecutive nl
    // (same (b,h)) land on one XCD.
    const int bid0 = blockIdx.x;                  // 0..511
    const int nl = (bid0 & 7) * 64 + (bid0 >> 3);
    const int l0 = (nl & 15) * QBLK;
    const int h  = (nl >> 4) & 7;
    const int b  = nl >> 7;
    const int t  = threadIdx.x;
    const int wv   = t >> 6;                      // 0..7
    const int lane = t & 63;
    const int quad = lane >> 4;
    const int nn   = lane & 15;

    // LDS: krot 32K | vts 8K | pss 16K = 56KB (2 blocks/CU)
    __shared__ __align__(16) unsigned char smem[57344];
    _Float16 (*krot)[256] = reinterpret_cast<_Float16 (*)[256]>(smem);          // 32KB
    _Float16 (*vts)[64]   = reinterpret_cast<_Float16 (*)[64]>(smem + 32768);   // 8KB
    _Float16 (*pss)[64]   = reinterpret_cast<_Float16 (*)[64]>(smem + 40960);   // 16KB
    float (*qtrc)[4] = reinterpret_cast<float (*)[4]>(smem + 40960);            // overlay pss
    float (*qtrs)[4] = reinterpret_cast<float (*)[4]>(smem + 40960 + 2048);
    float (*qstage)[64] = reinterpret_cast<float (*)[64]>(smem);                // overlay krot (32KB)

    const float* kb0 = kp  + ((size_t)((b * S_) * H_ + h)) * E_;
    const float* vb0 = vp  + ((size_t)((b * S_) * H_ + h)) * E_;
    const float* kob = ko  + ((size_t)((b * S_) * H_ + h)) * M_;
    const float* ktb = ktt + ((size_t)((b * S_) * H_ + h)) * M_;

    // K_rot build roles: 8 threads per key = 4 components x 2 e-halves
    const int key_r = t >> 3;       // 0..63
    const int ccr   = (t >> 1) & 3; // component
    const int eh    = t & 1;        // e-half within component
    const int swz   = key_r & 7;
    // V^T roles (upper 256 threads)
    const int tt = t & 255;
    const int kg = tt >> 4;         // key group (4 keys)
    const int eg = tt & 15;         // e group (4 e's)

    // ---- register pipeline: next tile's K slices, trig, V rows ----
    F4U kA[2], kB[2], omR, thR, vv[4];
    auto LOAD = [&](int s0) {
        const float* kr = kb0 + (size_t)(s0 + key_r) * (H_ * E_);
        kA[0].v = *(const float4*)(kr + ccr * 16 + eh * 8);            // a = k[cc]
        kA[1].v = *(const float4*)(kr + ccr * 16 + eh * 8 + 4);
        kB[0].v = *(const float4*)(kr + (ccr ^ 2) * 16 + eh * 8);      // b = k[cc^2]
        kB[1].v = *(const float4*)(kr + (ccr ^ 2) * 16 + eh * 8 + 4);
        omR.v = *(const float4*)(kob + (size_t)(s0 + key_r) * (H_ * M_));
        thR.v = *(const float4*)(ktb + (size_t)(s0 + key_r) * (H_ * M_));
        if (t >= 256) {
#pragma unroll
            for (int j = 0; j < 4; ++j)
                vv[j].v = *(const float4*)(vb0 + (size_t)(s0 + kg * 4 + j) * (H_ * E_) + eg * 4);
        }
    };
    LOAD(0);   // tile-0 loads fly under Q_rot construction

    // ---- build Q_rot A-fragments once per block (scale log2(e)/32 folded) ----
    // A-frag ks (K=32 step): kd = ks*32 + quad*8 + j -> m=ks>>1,
    // c = (ks&1)*2 + (quad>>1), i = (quad&1)*8 + j.
    f16x8 qa[8];
    {
        const float* qb = qp + ((size_t)((b * L_ + l0) * H_ + h)) * E_;
#pragma unroll
        for (int i = 0; i < 4; ++i) {
            int idx = t + NTH * i;                 // 0..2047
            int row = idx >> 4, c16 = idx & 15;
            *(float4*)&qstage[row][c16 * 4] =
                *(const float4*)(qb + (size_t)row * (H_ * E_) + c16 * 4);
        }
        {
            int row = t >> 2, m = t & 3;           // 128 rows x 4 m = 512
            size_t off = (size_t)((b * L_ + l0 + row) * H_ + h) * M_ + m;
            float ang = qo[off] * ((float)(l0 + row) * (1.0f / L_)) + qt[off];
            float sv, cv;
            __sincosf(ang, &sv, &cv);
            qtrc[row][m] = cv;
            qtrs[row][m] = sv;
        }
        __syncthreads();
        const int row = wv * 16 + nn;              // 0..127: A-frag row = lane&15
        const int i0 = (quad & 1) * 8;
        float sl0[8], sl1[8], sl2[8], sl3[8];
        *(float4*)&sl0[0] = *(float4*)&qstage[row][ 0 + i0];
        *(float4*)&sl0[4] = *(float4*)&qstage[row][ 4 + i0];
        *(float4*)&sl1[0] = *(float4*)&qstage[row][16 + i0];
        *(float4*)&sl1[4] = *(float4*)&qstage[row][20 + i0];
        *(float4*)&sl2[0] = *(float4*)&qstage[row][32 + i0];
        *(float4*)&sl2[4] = *(float4*)&qstage[row][36 + i0];
        *(float4*)&sl3[0] = *(float4*)&qstage[row][48 + i0];
        *(float4*)&sl3[4] = *(float4*)&qstage[row][52 + i0];
        // even ks -> c = quad>>1 (0 or 1); odd ks -> c+2.
        // Q signs: c0:-, c1:+, c2:+, c3:-   (b = q[c^1])
        const bool hiC = (quad & 2) != 0;
        float aE[8], bE[8], aO[8], bO[8];
#pragma unroll
        for (int j = 0; j < 8; ++j) {
            aE[j] = hiC ? sl1[j] : sl0[j];
            bE[j] = hiC ? sl0[j] : sl1[j];
            aO[j] = hiC ? sl3[j] : sl2[j];
            bO[j] = hiC ? sl2[j] : sl3[j];
        }
        F4U qc4, qs4;
        qc4.v = *(float4*)&qtrc[row][0];
        qs4.v = *(float4*)&qtrs[row][0];
        const float SC = 0.04508422017f;   // log2(e)/32
#pragma unroll
        for (int m = 0; m < 4; ++m) {
            float cm = qc4.f[m] * SC;
            float sm = qs4.f[m] * SC;
            float sE = hiC ? sm : -sm;     // c=1:+  c=0:-
            float vE[8], vO[8];
#pragma unroll
            for (int j = 0; j < 8; ++j) {
                vE[j] = fmaf(bE[j], sE, aE[j] * cm);
                vO[j] = fmaf(bO[j], -sE, aO[j] * cm);   // c=2:+  c=3:-
            }
            qa[2 * m]     = cvt8(vE);
            qa[2 * m + 1] = cvt8(vO);
        }
        __syncthreads();   // qstage (krot alias) + qtr (pss alias) now free
    }

    f32x4 Oacc[4] = {{0,0,0,0},{0,0,0,0},{0,0,0,0},{0,0,0,0}};
    float mrow = -1e30f;   // scalar: this lane's Q-row = wv*16 + nn
    float lrow = 0.f;
    const int xr0 = nn & 7;
    const int rowq = wv * 16 + nn;
    const int swq  = (nn & 7) ^ (nn >> 3);   // (rowq&7)^((rowq>>3)&1), wv*2 even

    for (int s0 = 0; s0 < S_; s0 += 64) {
        // ---- K_rot build from pipeline regs (K signs: c0:-, c1:-, c2:+, c3:+) ----
        {
            float af[8], bf[8];
#pragma unroll
            for (int i2 = 0; i2 < 4; ++i2) {
                af[i2]     = kA[0].f[i2];
                af[4 + i2] = kA[1].f[i2];
                bf[i2]     = kB[0].f[i2];
                bf[4 + i2] = kB[1].f[i2];
            }
            float posk = (float)(s0 + key_r) * (1.0f / S_);
            float kcv[4], ksv[4];
#pragma unroll
            for (int m = 0; m < 4; ++m) {
                float ang = omR.f[m] * posk + thR.f[m];
                __sincosf(ang, &ksv[m], &kcv[m]);
            }
            const float sgn = (ccr >= 2) ? 1.f : -1.f;
#pragma unroll
            for (int m = 0; m < 4; ++m) {
                float cm = kcv[m], sm = ksv[m] * sgn;
                float vals[8];
#pragma unroll
                for (int i = 0; i < 8; ++i)
                    vals[i] = fmaf(bf[i], sm, af[i] * cm);
                int ch = (m * 8) | ((ccr * 2 + eh) ^ swz);
                *(f16x8*)&krot[key_r][ch * 8] = cvt8(vals);
            }
        }
        // ---- V^T staging (upper 256 threads, 4x4 register-block transpose) ----
        if (t >= 256) {
#pragma unroll
            for (int e = 0; e < 4; ++e) {
                int row = eg * 4 + e;
                int ch = ((kg >> 1) ^ (row & 7));
                *(f16x4*)&vts[row][ch * 8 + (kg & 1) * 4] =
                    cvt4(vv[0].f[e], vv[1].f[e], vv[2].f[e], vv[3].f[e]);
            }
        }
        if (s0 + 64 < S_) LOAD(s0 + 64);   // next tile in flight across compute
        __syncthreads();

        // ---- QK^T swapped: A=K_frag, B=Q_frag -> D[key][qrow] ----
        // sc[kt2][r] = score(qrow = wv*16+nn, key = kt2*16 + quad*4 + r)
        float sc[4][4];
#pragma unroll
        for (int kt2 = 0; kt2 < 4; ++kt2) {
            const int keyb = kt2 * 16 + nn;
            f32x4 acc = {0, 0, 0, 0};
#pragma unroll
            for (int ks = 0; ks < 8; ++ks) {
                f16x8 bK = *(const f16x8*)&krot[keyb][((ks * 4 + quad) ^ xr0) * 8];
                acc = __builtin_amdgcn_mfma_f32_16x16x32_f16(bK, qa[ks], acc, 0, 0, 0);
            }
#pragma unroll
            for (int r = 0; r < 4; ++r) sc[kt2][r] = acc[r];
        }

        // ---- lane-local online softmax (base 2), defer-max THR=8 ----
        {
            float m01 = fmaxf(fmaxf(sc[0][0], sc[0][1]), fmaxf(sc[0][2], sc[0][3]));
            float m23 = fmaxf(fmaxf(sc[1][0], sc[1][1]), fmaxf(sc[1][2], sc[1][3]));
            float m45 = fmaxf(fmaxf(sc[2][0], sc[2][1]), fmaxf(sc[2][2], sc[2][3]));
            float m67 = fmaxf(fmaxf(sc[3][0], sc[3][1]), fmaxf(sc[3][2], sc[3][3]));
            float tm = fmaxf(fmaxf(m01, m23), fmaxf(m45, m67));
            tm = fmaxf(tm, __shfl_xor(tm, 16));
            tm = fmaxf(tm, __shfl_xor(tm, 32));   // all quads now hold row-max

            if (__any(tm > mrow + 8.0f)) {        // wave-uniform rescale path
                float mnew  = fmaxf(mrow, tm);
                float alpha = __builtin_amdgcn_exp2f(mrow - mnew);
                mrow = mnew;
                lrow *= alpha;
#pragma unroll
                for (int r = 0; r < 4; ++r) {
                    float ar = __shfl(alpha, quad * 4 + r, 64);
                    Oacc[0][r] *= ar; Oacc[1][r] *= ar;
                    Oacc[2][r] *= ar; Oacc[3][r] *= ar;
                }
            }

            float p[4][4];
#pragma unroll
            for (int kt2 = 0; kt2 < 4; ++kt2)
#pragma unroll
                for (int r = 0; r < 4; ++r)
                    p[kt2][r] = __builtin_amdgcn_exp2f(sc[kt2][r] - mrow);

            float s0s = (p[0][0] + p[0][1]) + (p[0][2] + p[0][3]);
            float s1s = (p[1][0] + p[1][1]) + (p[1][2] + p[1][3]);
            float s2s = (p[2][0] + p[2][1]) + (p[2][2] + p[2][3]);
            float s3s = (p[3][0] + p[3][1]) + (p[3][2] + p[3][3]);
            float psum = (s0s + s1s) + (s2s + s3s);
            psum += __shfl_xor(psum, 16);
            psum += __shfl_xor(psum, 32);
            lrow += psum;

            // ---- pack + write P (8 x ds_write_b32, bit3-fixed swizzle) ----
#pragma unroll
            for (int kt2 = 0; kt2 < 4; ++kt2)
#pragma unroll
                for (int d2 = 0; d2 < 2; ++d2) {
                    fp16x2 pkv = __builtin_amdgcn_cvt_pkrtz(p[kt2][2 * d2], p[kt2][2 * d2 + 1]);
                    int key0 = kt2 * 16 + quad * 4 + 2 * d2;
                    int ch = (key0 >> 3) ^ swq;
                    *(fp16x2*)&pss[rowq][ch * 8 + (key0 & 7)] = pkv;
                }
        }

        // ---- PV (wave-local P round-trip, no barrier needed) ----
        {
            const int prow = rowq;
            const int swp = swq;
#pragma unroll
            for (int ks2 = 0; ks2 < 2; ++ks2) {
                f16x8 pf = *(const f16x8*)&pss[prow][((quad + 4 * ks2) ^ swp) * 8];
#pragma unroll
                for (int et = 0; et < 4; ++et) {
                    int e = et * 16 + nn;
                    f16x8 vf = *(const f16x8*)&vts[e][((quad + 4 * ks2) ^ (e & 7)) * 8];
                    Oacc[et] = __builtin_amdgcn_mfma_f32_16x16x32_f16(pf, vf, Oacc[et], 0, 0, 0);
                }
            }
        }
        __syncthreads();   // all krot/vts/pss reads done before next staging
    }

    // ---- epilogue ----
    float* ob = out + ((size_t)((b * L_ + l0) * H_ + h)) * E_;
#pragma unroll
    for (int r = 0; r < 4; ++r) {
        float lr = __shfl(lrow, quad * 4 + r, 64);
        float inv = 1.0f / lr;
        int row = wv * 16 + quad * 4 + r;          // 0..127
#pragma unroll
        for (int et = 0; et < 4; ++et)
            ob[(size_t)row * (H_ * E_) + et * 16 + nn] = Oacc[et][r] * inv;
    }
}

extern "C" void kernel_launch(void* const* d_in, const int* in_sizes, int n_in,
                              void* d_out, int out_size, void* d_ws, size_t ws_size,
                              hipStream_t stream) {
    const float* qp = (const float*)d_in[0];
    const float* kp = (const float*)d_in[1];
    const float* vp = (const float*)d_in[2];
    const float* qo = (const float*)d_in[3];
    const float* qt = (const float*)d_in[4];
    const float* ko = (const float*)d_in[5];
    const float* kt = (const float*)d_in[6];
    float* out = (float*)d_out;

    qattn6<<<dim3(B_ * H_ * (L_ / QBLK)), dim3(NTH), 0, stream>>>(
        qp, kp, vp, qo, qt, ko, kt, out);
}

// Round 6
// 196.658 us; speedup vs baseline: 3.1554x; 1.2579x over previous
//
#include <hip/hip_runtime.h>
#include <math.h>

// QuaternionAttention B=4, L=S=2048, H=8, E=64, M=4 (fp32 in/out).
// Round 14: 32-rows-per-wave operand reuse. Round-13 (193.7us dispatch)
// counters: MfmaUtil 18.7 / VALU 33 / conflicts 110K cyc/CU -> LDS-read-BW
// bound: each wave read the whole 32KB krot tile for only 16 Q-rows (1KB
// ds_read_b128 per 5-cyc MFMA). Now QBLK=256, 8 waves x (32 rows x 64 keys):
// two Q_rot A-frag sets per wave (qa[2][8], +32 VGPR) so every bK read feeds
// 2 MFMAs -> QK LDS reads per row halved; V^T reads shared across row-sets
// (halved); K_rot rebuilds per (b,h) 16 -> 8 (build VALU per CU halved).
// All frag layouts / swizzles / staging / softmax / PV bodies are the proven
// round-13 code wrapped in a set-loop (swq is set-invariant). LDS 72KB
// (krot 32K | vts 8K | pss[256] 32K), grid 256 = 1 block/CU, XCD swizzle
// groups 4 (b,h) per XCD.

#define B_ 4
#define L_ 2048
#define S_ 2048
#define H_ 8
#define E_ 64
#define M_ 4
#define QBLK 256
#define NTH 512

typedef _Float16 f16x4 __attribute__((ext_vector_type(4)));
typedef _Float16 f16x8 __attribute__((ext_vector_type(8)));
typedef __fp16 fp16x2 __attribute__((ext_vector_type(2)));   // cvt_pkrtz return type
typedef float f32x4 __attribute__((ext_vector_type(4)));

union H4U { f16x4 h; fp16x2 p[2]; };
union H8U { f16x8 h; fp16x2 p[4]; };
union F4U { float4 v; float f[4]; };

__device__ __forceinline__ f16x4 cvt4(float x, float y, float z, float w) {
    H4U r;
    r.p[0] = __builtin_amdgcn_cvt_pkrtz(x, y);
    r.p[1] = __builtin_amdgcn_cvt_pkrtz(z, w);
    return r.h;
}
__device__ __forceinline__ f16x8 cvt8(const float* v) {
    H8U r;
#pragma unroll
    for (int i = 0; i < 4; ++i) r.p[i] = __builtin_amdgcn_cvt_pkrtz(v[2 * i], v[2 * i + 1]);
    return r.h;
}

__global__ __launch_bounds__(NTH)
void qattn7(const float* __restrict__ qp, const float* __restrict__ kp,
            const float* __restrict__ vp,
            const float* __restrict__ qo, const float* __restrict__ qt,
            const float* __restrict__ ko, const float* __restrict__ ktt,
            float* __restrict__ out)
{
    // XCD-chunked swizzle (256 blocks, bijective): bid&7 = XCD under
    // round-robin dispatch; each XCD gets 32 consecutive nl = 4 (b,h) groups.
    const int bid0 = blockIdx.x;                  // 0..255
    const int nl = (bid0 & 7) * 32 + (bid0 >> 3);
    const int l0 = (nl & 7) * QBLK;
    const int h  = (nl >> 3) & 7;
    const int b  = nl >> 6;
    const int t  = threadIdx.x;
    const int wv   = t >> 6;                      // 0..7
    const int lane = t & 63;
    const int quad = lane >> 4;
    const int nn   = lane & 15;

    // LDS: krot 32K | vts 8K | pss 32K = 72KB (1 block/CU)
    __shared__ __align__(16) unsigned char smem[73728];
    _Float16 (*krot)[256] = reinterpret_cast<_Float16 (*)[256]>(smem);          // 32KB
    _Float16 (*vts)[64]   = reinterpret_cast<_Float16 (*)[64]>(smem + 32768);   // 8KB
    _Float16 (*pss)[64]   = reinterpret_cast<_Float16 (*)[64]>(smem + 40960);   // 32KB [256][64]
    float (*qstage)[64] = reinterpret_cast<float (*)[64]>(smem);                // overlay 0..64KB
    float (*qtrc)[4] = reinterpret_cast<float (*)[4]>(smem + 65536);            // 4KB
    float (*qtrs)[4] = reinterpret_cast<float (*)[4]>(smem + 65536 + 4096);     // 4KB

    const float* kb0 = kp  + ((size_t)((b * S_) * H_ + h)) * E_;
    const float* vb0 = vp  + ((size_t)((b * S_) * H_ + h)) * E_;
    const float* kob = ko  + ((size_t)((b * S_) * H_ + h)) * M_;
    const float* ktb = ktt + ((size_t)((b * S_) * H_ + h)) * M_;

    // K_rot build roles: 8 threads per key = 4 components x 2 e-halves
    const int key_r = t >> 3;       // 0..63
    const int ccr   = (t >> 1) & 3; // component
    const int eh    = t & 1;        // e-half within component
    const int swz   = key_r & 7;
    // V^T roles (upper 256 threads)
    const int tt = t & 255;
    const int kg = tt >> 4;         // key group (4 keys)
    const int eg = tt & 15;         // e group (4 e's)

    // ---- register pipeline: next tile's K slices, trig, V rows ----
    F4U kA[2], kB[2], omR, thR, vv[4];
    auto LOAD = [&](int s0) {
        const float* kr = kb0 + (size_t)(s0 + key_r) * (H_ * E_);
        kA[0].v = *(const float4*)(kr + ccr * 16 + eh * 8);            // a = k[cc]
        kA[1].v = *(const float4*)(kr + ccr * 16 + eh * 8 + 4);
        kB[0].v = *(const float4*)(kr + (ccr ^ 2) * 16 + eh * 8);      // b = k[cc^2]
        kB[1].v = *(const float4*)(kr + (ccr ^ 2) * 16 + eh * 8 + 4);
        omR.v = *(const float4*)(kob + (size_t)(s0 + key_r) * (H_ * M_));
        thR.v = *(const float4*)(ktb + (size_t)(s0 + key_r) * (H_ * M_));
        if (t >= 256) {
#pragma unroll
            for (int j = 0; j < 4; ++j)
                vv[j].v = *(const float4*)(vb0 + (size_t)(s0 + kg * 4 + j) * (H_ * E_) + eg * 4);
        }
    };
    LOAD(0);   // tile-0 loads fly under Q_rot construction

    // ---- build Q_rot A-fragments once per block (scale log2(e)/32 folded) ----
    // Two sets per wave: set s covers rows wv*32 + s*16 + (0..15).
    f16x8 qa[2][8];
    {
        const float* qb = qp + ((size_t)((b * L_ + l0) * H_ + h)) * E_;
#pragma unroll
        for (int i = 0; i < 8; ++i) {
            int idx = t + NTH * i;                 // 0..4095
            int row = idx >> 4, c16 = idx & 15;
            *(float4*)&qstage[row][c16 * 4] =
                *(const float4*)(qb + (size_t)row * (H_ * E_) + c16 * 4);
        }
        {
            int row = t >> 1, m0 = (t & 1) * 2;    // 256 rows x 2 m-pairs
#pragma unroll
            for (int dm = 0; dm < 2; ++dm) {
                int m = m0 + dm;
                size_t off = (size_t)((b * L_ + l0 + row) * H_ + h) * M_ + m;
                float ang = qo[off] * ((float)(l0 + row) * (1.0f / L_)) + qt[off];
                float sv, cv;
                __sincosf(ang, &sv, &cv);
                qtrc[row][m] = cv;
                qtrs[row][m] = sv;
            }
        }
        __syncthreads();
#pragma unroll
        for (int set = 0; set < 2; ++set) {
            const int row = wv * 32 + set * 16 + nn;   // A-frag row = lane&15
            const int i0 = (quad & 1) * 8;
            float sl0[8], sl1[8], sl2[8], sl3[8];
            *(float4*)&sl0[0] = *(float4*)&qstage[row][ 0 + i0];
            *(float4*)&sl0[4] = *(float4*)&qstage[row][ 4 + i0];
            *(float4*)&sl1[0] = *(float4*)&qstage[row][16 + i0];
            *(float4*)&sl1[4] = *(float4*)&qstage[row][20 + i0];
            *(float4*)&sl2[0] = *(float4*)&qstage[row][32 + i0];
            *(float4*)&sl2[4] = *(float4*)&qstage[row][36 + i0];
            *(float4*)&sl3[0] = *(float4*)&qstage[row][48 + i0];
            *(float4*)&sl3[4] = *(float4*)&qstage[row][52 + i0];
            // even ks -> c = quad>>1 (0 or 1); odd ks -> c+2.
            // Q signs: c0:-, c1:+, c2:+, c3:-   (b = q[c^1])
            const bool hiC = (quad & 2) != 0;
            float aE[8], bE[8], aO[8], bO[8];
#pragma unroll
            for (int j = 0; j < 8; ++j) {
                aE[j] = hiC ? sl1[j] : sl0[j];
                bE[j] = hiC ? sl0[j] : sl1[j];
                aO[j] = hiC ? sl3[j] : sl2[j];
                bO[j] = hiC ? sl2[j] : sl3[j];
            }
            F4U qc4, qs4;
            qc4.v = *(float4*)&qtrc[row][0];
            qs4.v = *(float4*)&qtrs[row][0];
            const float SC = 0.04508422017f;   // log2(e)/32
#pragma unroll
            for (int m = 0; m < 4; ++m) {
                float cm = qc4.f[m] * SC;
                float sm = qs4.f[m] * SC;
                float sE = hiC ? sm : -sm;     // c=1:+  c=0:-
                float vE[8], vO[8];
#pragma unroll
                for (int j = 0; j < 8; ++j) {
                    vE[j] = fmaf(bE[j], sE, aE[j] * cm);
                    vO[j] = fmaf(bO[j], -sE, aO[j] * cm);   // c=2:+  c=3:-
                }
                qa[set][2 * m]     = cvt8(vE);
                qa[set][2 * m + 1] = cvt8(vO);
            }
        }
        __syncthreads();   // qstage/qtr overlays now free
    }

    f32x4 Oacc[2][4] = {{{0,0,0,0},{0,0,0,0},{0,0,0,0},{0,0,0,0}},
                        {{0,0,0,0},{0,0,0,0},{0,0,0,0},{0,0,0,0}}};
    float mrow[2] = {-1e30f, -1e30f};   // per set: lane's Q-row = wv*32+set*16+nn
    float lrow[2] = {0.f, 0.f};
    const int xr0 = nn & 7;
    const int swq = (nn & 7) ^ (nn >> 3);   // (row&7)^((row>>3)&1), set-invariant

    for (int s0 = 0; s0 < S_; s0 += 64) {
        // ---- K_rot build from pipeline regs (K signs: c0:-, c1:-, c2:+, c3:+) ----
        {
            float af[8], bf[8];
#pragma unroll
            for (int i2 = 0; i2 < 4; ++i2) {
                af[i2]     = kA[0].f[i2];
                af[4 + i2] = kA[1].f[i2];
                bf[i2]     = kB[0].f[i2];
                bf[4 + i2] = kB[1].f[i2];
            }
            float posk = (float)(s0 + key_r) * (1.0f / S_);
            float kcv[4], ksv[4];
#pragma unroll
            for (int m = 0; m < 4; ++m) {
                float ang = omR.f[m] * posk + thR.f[m];
                __sincosf(ang, &ksv[m], &kcv[m]);
            }
            const float sgn = (ccr >= 2) ? 1.f : -1.f;
#pragma unroll
            for (int m = 0; m < 4; ++m) {
                float cm = kcv[m], sm = ksv[m] * sgn;
                float vals[8];
#pragma unroll
                for (int i = 0; i < 8; ++i)
                    vals[i] = fmaf(bf[i], sm, af[i] * cm);
                int ch = (m * 8) | ((ccr * 2 + eh) ^ swz);
                *(f16x8*)&krot[key_r][ch * 8] = cvt8(vals);
            }
        }
        // ---- V^T staging (upper 256 threads, 4x4 register-block transpose) ----
        if (t >= 256) {
#pragma unroll
            for (int e = 0; e < 4; ++e) {
                int row = eg * 4 + e;
                int ch = ((kg >> 1) ^ (row & 7));
                *(f16x4*)&vts[row][ch * 8 + (kg & 1) * 4] =
                    cvt4(vv[0].f[e], vv[1].f[e], vv[2].f[e], vv[3].f[e]);
            }
        }
        if (s0 + 64 < S_) LOAD(s0 + 64);   // next tile in flight across compute
        __syncthreads();

        // ---- QK^T swapped: A=K_frag, B=Q_frag -> D[key][qrow]; bK feeds 2 sets ----
        float sc[2][4][4];
#pragma unroll
        for (int kt2 = 0; kt2 < 4; ++kt2) {
            const int keyb = kt2 * 16 + nn;
            f32x4 acc0 = {0, 0, 0, 0}, acc1 = {0, 0, 0, 0};
#pragma unroll
            for (int ks = 0; ks < 8; ++ks) {
                f16x8 bK = *(const f16x8*)&krot[keyb][((ks * 4 + quad) ^ xr0) * 8];
                acc0 = __builtin_amdgcn_mfma_f32_16x16x32_f16(bK, qa[0][ks], acc0, 0, 0, 0);
                acc1 = __builtin_amdgcn_mfma_f32_16x16x32_f16(bK, qa[1][ks], acc1, 0, 0, 0);
            }
#pragma unroll
            for (int r = 0; r < 4; ++r) { sc[0][kt2][r] = acc0[r]; sc[1][kt2][r] = acc1[r]; }
        }

        // ---- lane-local online softmax (base 2), defer-max THR=8, per set ----
#pragma unroll
        for (int set = 0; set < 2; ++set) {
            const int rowq = wv * 32 + set * 16 + nn;
            float m01 = fmaxf(fmaxf(sc[set][0][0], sc[set][0][1]), fmaxf(sc[set][0][2], sc[set][0][3]));
            float m23 = fmaxf(fmaxf(sc[set][1][0], sc[set][1][1]), fmaxf(sc[set][1][2], sc[set][1][3]));
            float m45 = fmaxf(fmaxf(sc[set][2][0], sc[set][2][1]), fmaxf(sc[set][2][2], sc[set][2][3]));
            float m67 = fmaxf(fmaxf(sc[set][3][0], sc[set][3][1]), fmaxf(sc[set][3][2], sc[set][3][3]));
            float tm = fmaxf(fmaxf(m01, m23), fmaxf(m45, m67));
            tm = fmaxf(tm, __shfl_xor(tm, 16));
            tm = fmaxf(tm, __shfl_xor(tm, 32));   // all quads now hold row-max

            if (__any(tm > mrow[set] + 8.0f)) {   // wave-uniform rescale path
                float mnew  = fmaxf(mrow[set], tm);
                float alpha = __builtin_amdgcn_exp2f(mrow[set] - mnew);
                mrow[set] = mnew;
                lrow[set] *= alpha;
#pragma unroll
                for (int r = 0; r < 4; ++r) {
                    float ar = __shfl(alpha, quad * 4 + r, 64);
                    Oacc[set][0][r] *= ar; Oacc[set][1][r] *= ar;
                    Oacc[set][2][r] *= ar; Oacc[set][3][r] *= ar;
                }
            }

            float p[4][4];
#pragma unroll
            for (int kt2 = 0; kt2 < 4; ++kt2)
#pragma unroll
                for (int r = 0; r < 4; ++r)
                    p[kt2][r] = __builtin_amdgcn_exp2f(sc[set][kt2][r] - mrow[set]);

            float s0s = (p[0][0] + p[0][1]) + (p[0][2] + p[0][3]);
            float s1s = (p[1][0] + p[1][1]) + (p[1][2] + p[1][3]);
            float s2s = (p[2][0] + p[2][1]) + (p[2][2] + p[2][3]);
            float s3s = (p[3][0] + p[3][1]) + (p[3][2] + p[3][3]);
            float psum = (s0s + s1s) + (s2s + s3s);
            psum += __shfl_xor(psum, 16);
            psum += __shfl_xor(psum, 32);
            lrow[set] += psum;

            // ---- pack + write P (8 x ds_write_b32, bit3-fixed swizzle) ----
#pragma unroll
            for (int kt2 = 0; kt2 < 4; ++kt2)
#pragma unroll
                for (int d2 = 0; d2 < 2; ++d2) {
                    fp16x2 pkv = __builtin_amdgcn_cvt_pkrtz(p[kt2][2 * d2], p[kt2][2 * d2 + 1]);
                    int key0 = kt2 * 16 + quad * 4 + 2 * d2;
                    int ch = (key0 >> 3) ^ swq;
                    *(fp16x2*)&pss[rowq][ch * 8 + (key0 & 7)] = pkv;
                }
        }

        // ---- PV (wave-local P round-trip; vf shared across sets) ----
        {
            const int pr0 = wv * 32 + nn;
#pragma unroll
            for (int ks2 = 0; ks2 < 2; ++ks2) {
                f16x8 pf0 = *(const f16x8*)&pss[pr0     ][((quad + 4 * ks2) ^ swq) * 8];
                f16x8 pf1 = *(const f16x8*)&pss[pr0 + 16][((quad + 4 * ks2) ^ swq) * 8];
#pragma unroll
                for (int et = 0; et < 4; ++et) {
                    int e = et * 16 + nn;
                    f16x8 vf = *(const f16x8*)&vts[e][((quad + 4 * ks2) ^ (e & 7)) * 8];
                    Oacc[0][et] = __builtin_amdgcn_mfma_f32_16x16x32_f16(pf0, vf, Oacc[0][et], 0, 0, 0);
                    Oacc[1][et] = __builtin_amdgcn_mfma_f32_16x16x32_f16(pf1, vf, Oacc[1][et], 0, 0, 0);
                }
            }
        }
        __syncthreads();   // all krot/vts/pss reads done before next staging
    }

    // ---- epilogue ----
    float* ob = out + ((size_t)((b * L_ + l0) * H_ + h)) * E_;
#pragma unroll
    for (int set = 0; set < 2; ++set)
#pragma unroll
        for (int r = 0; r < 4; ++r) {
            float lr = __shfl(lrow[set], quad * 4 + r, 64);
            float inv = 1.0f / lr;
            int row = wv * 32 + set * 16 + quad * 4 + r;   // 0..255
#pragma unroll
            for (int et = 0; et < 4; ++et)
                ob[(size_t)row * (H_ * E_) + et * 16 + nn] = Oacc[set][et][r] * inv;
        }
}

extern "C" void kernel_launch(void* const* d_in, const int* in_sizes, int n_in,
                              void* d_out, int out_size, void* d_ws, size_t ws_size,
                              hipStream_t stream) {
    const float* qp = (const float*)d_in[0];
    const float* kp = (const float*)d_in[1];
    const float* vp = (const float*)d_in[2];
    const float* qo = (const float*)d_in[3];
    const float* qt = (const float*)d_in[4];
    const float* ko = (const float*)d_in[5];
    const float* kt = (const float*)d_in[6];
    float* out = (float*)d_out;

    qattn7<<<dim3(B_ * H_ * (L_ / QBLK)), dim3(NTH), 0, stream>>>(
        qp, kp, vp, qo, qt, ko, kt, out);
}

// Round 7
// 193.000 us; speedup vs baseline: 3.2152x; 1.0190x over previous
//
#include <hip/hip_runtime.h>
#include <math.h>

// QuaternionAttention B=4, L=S=2048, H=8, E=64, M=4 (fp32 in/out).
// Round 15: single-barrier double-buffered pipeline on the round-14 base
// (136us dispatch: QBLK=256/NTH=512, 2-set operand reuse, swapped-QK
// lane-local softmax). Round-14 counters: MFMA 27 / VALU 37 / ~36% no-issue
// -> barrier lock-step + libm sincos + P-store count are the levers.
//   1) krot+vts double-buffered (LDS 72->112KB, still 1 block/CU): compute
//      reads buf[ti&1], build writes buf^1 -> ONE barrier/tile (was 2);
//      per-wave order QK -> build(t+1) -> softmax -> PV so build VALU of one
//      wave overlaps MFMA of another; s_setprio(1) around MFMA clusters (T5).
//   2) raw v_sin/v_cos (revolutions; |ang|<=~12 -> |rev|<=2, in HW range)
//      replaces __sincosf's range-reduction in K-build (x4/thread/tile) and
//      Q-build.
//   3) P stores packed f16x4: 8 -> 4 ds_writes per set (same swizzle: keys
//      quad*4..+3 share one chunk).
// All fragment layouts / swizzles / staging / softmax bodies unchanged.

#define B_ 4
#define L_ 2048
#define S_ 2048
#define H_ 8
#define E_ 64
#define M_ 4
#define QBLK 256
#define NTH 512
#define NTILES 32

#define KROT_OFF 0          // 2 x 32KB
#define VTS_OFF  65536      // 2 x 8KB
#define PSS_OFF  81920      // 32KB
#define SMEM_BYTES 114688

typedef _Float16 f16x4 __attribute__((ext_vector_type(4)));
typedef _Float16 f16x8 __attribute__((ext_vector_type(8)));
typedef __fp16 fp16x2 __attribute__((ext_vector_type(2)));   // cvt_pkrtz return type
typedef float f32x4 __attribute__((ext_vector_type(4)));

union H4U { f16x4 h; fp16x2 p[2]; };
union H8U { f16x8 h; fp16x2 p[4]; };
union F4U { float4 v; float f[4]; };

#if __has_builtin(__builtin_amdgcn_sinf) && __has_builtin(__builtin_amdgcn_cosf)
#define FSINCOS(ang, s, c) do { float _rv = (ang) * 0.15915494309189535f; \
    (s) = __builtin_amdgcn_sinf(_rv); (c) = __builtin_amdgcn_cosf(_rv); } while (0)
#else
#define FSINCOS(ang, s, c) __sincosf((ang), &(s), &(c))
#endif

__device__ __forceinline__ f16x4 cvt4(float x, float y, float z, float w) {
    H4U r;
    r.p[0] = __builtin_amdgcn_cvt_pkrtz(x, y);
    r.p[1] = __builtin_amdgcn_cvt_pkrtz(z, w);
    return r.h;
}
__device__ __forceinline__ f16x8 cvt8(const float* v) {
    H8U r;
#pragma unroll
    for (int i = 0; i < 4; ++i) r.p[i] = __builtin_amdgcn_cvt_pkrtz(v[2 * i], v[2 * i + 1]);
    return r.h;
}

__global__ __launch_bounds__(NTH)
void qattn8(const float* __restrict__ qp, const float* __restrict__ kp,
            const float* __restrict__ vp,
            const float* __restrict__ qo, const float* __restrict__ qt,
            const float* __restrict__ ko, const float* __restrict__ ktt,
            float* __restrict__ out)
{
    // XCD-chunked swizzle (256 blocks, bijective): each XCD gets 32
    // consecutive nl = 4 (b,h) groups.
    const int bid0 = blockIdx.x;                  // 0..255
    const int nl = (bid0 & 7) * 32 + (bid0 >> 3);
    const int l0 = (nl & 7) * QBLK;
    const int h  = (nl >> 3) & 7;
    const int b  = nl >> 6;
    const int t  = threadIdx.x;
    const int wv   = t >> 6;                      // 0..7
    const int lane = t & 63;
    const int quad = lane >> 4;
    const int nn   = lane & 15;

    __shared__ __align__(16) unsigned char smem[SMEM_BYTES];
    _Float16 (*pss)[64] = reinterpret_cast<_Float16 (*)[64]>(smem + PSS_OFF);   // 32KB
    float (*qstage)[64] = reinterpret_cast<float (*)[64]>(smem);                // overlay krot bufs (64KB)
    float (*qtrc)[4] = reinterpret_cast<float (*)[4]>(smem + PSS_OFF);          // overlay pss
    float (*qtrs)[4] = reinterpret_cast<float (*)[4]>(smem + PSS_OFF + 4096);

    const float* kb0 = kp  + ((size_t)((b * S_) * H_ + h)) * E_;
    const float* vb0 = vp  + ((size_t)((b * S_) * H_ + h)) * E_;
    const float* kob = ko  + ((size_t)((b * S_) * H_ + h)) * M_;
    const float* ktb = ktt + ((size_t)((b * S_) * H_ + h)) * M_;

    // K_rot build roles: 8 threads per key = 4 components x 2 e-halves
    const int key_r = t >> 3;       // 0..63
    const int ccr   = (t >> 1) & 3; // component
    const int eh    = t & 1;        // e-half within component
    const int swz   = key_r & 7;
    // V^T roles (upper 256 threads)
    const int tt = t & 255;
    const int kg = tt >> 4;         // key group (4 keys)
    const int eg = tt & 15;         // e group (4 e's)

    // ---- register pipeline: next tile's K slices, trig, V rows ----
    F4U kA[2], kB[2], omR, thR, vv[4];
    auto LOAD = [&](int s0) {
        const float* kr = kb0 + (size_t)(s0 + key_r) * (H_ * E_);
        kA[0].v = *(const float4*)(kr + ccr * 16 + eh * 8);            // a = k[cc]
        kA[1].v = *(const float4*)(kr + ccr * 16 + eh * 8 + 4);
        kB[0].v = *(const float4*)(kr + (ccr ^ 2) * 16 + eh * 8);      // b = k[cc^2]
        kB[1].v = *(const float4*)(kr + (ccr ^ 2) * 16 + eh * 8 + 4);
        omR.v = *(const float4*)(kob + (size_t)(s0 + key_r) * (H_ * M_));
        thR.v = *(const float4*)(ktb + (size_t)(s0 + key_r) * (H_ * M_));
        if (t >= 256) {
#pragma unroll
            for (int j = 0; j < 4; ++j)
                vv[j].v = *(const float4*)(vb0 + (size_t)(s0 + kg * 4 + j) * (H_ * E_) + eg * 4);
        }
    };

    // ---- build K_rot + V^T into the given LDS buffers from pipeline regs ----
    auto BUILD = [&](int s0, int koff, int voff) {
        _Float16 (*krw)[256] = reinterpret_cast<_Float16 (*)[256]>(smem + koff);
        _Float16 (*vtw)[64]  = reinterpret_cast<_Float16 (*)[64]>(smem + voff);
        {   // K signs: c0:-, c1:-, c2:+, c3:+
            float af[8], bf[8];
#pragma unroll
            for (int i2 = 0; i2 < 4; ++i2) {
                af[i2]     = kA[0].f[i2];
                af[4 + i2] = kA[1].f[i2];
                bf[i2]     = kB[0].f[i2];
                bf[4 + i2] = kB[1].f[i2];
            }
            float posk = (float)(s0 + key_r) * (1.0f / S_);
            float kcv[4], ksv[4];
#pragma unroll
            for (int m = 0; m < 4; ++m) {
                float ang = fmaf(omR.f[m], posk, thR.f[m]);
                FSINCOS(ang, ksv[m], kcv[m]);
            }
            const float sgn = (ccr >= 2) ? 1.f : -1.f;
#pragma unroll
            for (int m = 0; m < 4; ++m) {
                float cm = kcv[m], sm = ksv[m] * sgn;
                float vals[8];
#pragma unroll
                for (int i = 0; i < 8; ++i)
                    vals[i] = fmaf(bf[i], sm, af[i] * cm);
                int ch = (m * 8) | ((ccr * 2 + eh) ^ swz);
                *(f16x8*)&krw[key_r][ch * 8] = cvt8(vals);
            }
        }
        if (t >= 256) {   // V^T 4x4 register-block transpose
#pragma unroll
            for (int e = 0; e < 4; ++e) {
                int row = eg * 4 + e;
                int ch = ((kg >> 1) ^ (row & 7));
                *(f16x4*)&vtw[row][ch * 8 + (kg & 1) * 4] =
                    cvt4(vv[0].f[e], vv[1].f[e], vv[2].f[e], vv[3].f[e]);
            }
        }
    };

    LOAD(0);   // tile-0 loads fly under Q_rot construction

    // ---- build Q_rot A-fragments once per block (scale log2(e)/32 folded) ----
    // Two sets per wave: set s covers rows wv*32 + s*16 + (0..15).
    f16x8 qa[2][8];
    {
        const float* qb = qp + ((size_t)((b * L_ + l0) * H_ + h)) * E_;
#pragma unroll
        for (int i = 0; i < 8; ++i) {
            int idx = t + NTH * i;                 // 0..4095
            int row = idx >> 4, c16 = idx & 15;
            *(float4*)&qstage[row][c16 * 4] =
                *(const float4*)(qb + (size_t)row * (H_ * E_) + c16 * 4);
        }
        {
            int row = t >> 1, m0 = (t & 1) * 2;    // 256 rows x 2 m-pairs
#pragma unroll
            for (int dm = 0; dm < 2; ++dm) {
                int m = m0 + dm;
                size_t off = (size_t)((b * L_ + l0 + row) * H_ + h) * M_ + m;
                float ang = qo[off] * ((float)(l0 + row) * (1.0f / L_)) + qt[off];
                float sv, cv;
                FSINCOS(ang, sv, cv);
                qtrc[row][m] = cv;
                qtrs[row][m] = sv;
            }
        }
        __syncthreads();
#pragma unroll
        for (int set = 0; set < 2; ++set) {
            const int row = wv * 32 + set * 16 + nn;   // A-frag row = lane&15
            const int i0 = (quad & 1) * 8;
            float sl0[8], sl1[8], sl2[8], sl3[8];
            *(float4*)&sl0[0] = *(float4*)&qstage[row][ 0 + i0];
            *(float4*)&sl0[4] = *(float4*)&qstage[row][ 4 + i0];
            *(float4*)&sl1[0] = *(float4*)&qstage[row][16 + i0];
            *(float4*)&sl1[4] = *(float4*)&qstage[row][20 + i0];
            *(float4*)&sl2[0] = *(float4*)&qstage[row][32 + i0];
            *(float4*)&sl2[4] = *(float4*)&qstage[row][36 + i0];
            *(float4*)&sl3[0] = *(float4*)&qstage[row][48 + i0];
            *(float4*)&sl3[4] = *(float4*)&qstage[row][52 + i0];
            // even ks -> c = quad>>1 (0 or 1); odd ks -> c+2.
            // Q signs: c0:-, c1:+, c2:+, c3:-   (b = q[c^1])
            const bool hiC = (quad & 2) != 0;
            float aE[8], bE[8], aO[8], bO[8];
#pragma unroll
            for (int j = 0; j < 8; ++j) {
                aE[j] = hiC ? sl1[j] : sl0[j];
                bE[j] = hiC ? sl0[j] : sl1[j];
                aO[j] = hiC ? sl3[j] : sl2[j];
                bO[j] = hiC ? sl2[j] : sl3[j];
            }
            F4U qc4, qs4;
            qc4.v = *(float4*)&qtrc[row][0];
            qs4.v = *(float4*)&qtrs[row][0];
            const float SC = 0.04508422017f;   // log2(e)/32
#pragma unroll
            for (int m = 0; m < 4; ++m) {
                float cm = qc4.f[m] * SC;
                float sm = qs4.f[m] * SC;
                float sE = hiC ? sm : -sm;     // c=1:+  c=0:-
                float vE[8], vO[8];
#pragma unroll
                for (int j = 0; j < 8; ++j) {
                    vE[j] = fmaf(bE[j], sE, aE[j] * cm);
                    vO[j] = fmaf(bO[j], -sE, aO[j] * cm);   // c=2:+  c=3:-
                }
                qa[set][2 * m]     = cvt8(vE);
                qa[set][2 * m + 1] = cvt8(vO);
            }
        }
        __syncthreads();   // qstage/qtr overlays now free
    }

    f32x4 Oacc[2][4] = {{{0,0,0,0},{0,0,0,0},{0,0,0,0},{0,0,0,0}},
                        {{0,0,0,0},{0,0,0,0},{0,0,0,0},{0,0,0,0}}};
    float mrow[2] = {-1e30f, -1e30f};   // per set: lane's Q-row = wv*32+set*16+nn
    float lrow[2] = {0.f, 0.f};
    const int xr0 = nn & 7;
    const int swq = (nn & 7) ^ (nn >> 3);   // (row&7)^((row>>3)&1), set-invariant

    // ---- prologue: tile 0 into buf0, prefetch tile 1 ----
    BUILD(0, KROT_OFF, VTS_OFF);
    LOAD(64);
    __syncthreads();

    for (int ti = 0; ti < NTILES; ++ti) {
        _Float16 (*krot)[256] = reinterpret_cast<_Float16 (*)[256]>(
            smem + KROT_OFF + (ti & 1) * 32768);
        _Float16 (*vts)[64] = reinterpret_cast<_Float16 (*)[64]>(
            smem + VTS_OFF + (ti & 1) * 8192);

        // ---- QK^T swapped: A=K_frag, B=Q_frag -> D[key][qrow]; bK feeds 2 sets ----
        float sc[2][4][4];
        __builtin_amdgcn_s_setprio(1);
#pragma unroll
        for (int kt2 = 0; kt2 < 4; ++kt2) {
            const int keyb = kt2 * 16 + nn;
            f32x4 acc0 = {0, 0, 0, 0}, acc1 = {0, 0, 0, 0};
#pragma unroll
            for (int ks = 0; ks < 8; ++ks) {
                f16x8 bK = *(const f16x8*)&krot[keyb][((ks * 4 + quad) ^ xr0) * 8];
                acc0 = __builtin_amdgcn_mfma_f32_16x16x32_f16(bK, qa[0][ks], acc0, 0, 0, 0);
                acc1 = __builtin_amdgcn_mfma_f32_16x16x32_f16(bK, qa[1][ks], acc1, 0, 0, 0);
            }
#pragma unroll
            for (int r = 0; r < 4; ++r) { sc[0][kt2][r] = acc0[r]; sc[1][kt2][r] = acc1[r]; }
        }
        __builtin_amdgcn_s_setprio(0);

        // ---- build tile ti+1 into the other buffer (overlaps other waves' MFMA) ----
        if (ti + 1 < NTILES) {
            BUILD((ti + 1) * 64, KROT_OFF + ((ti + 1) & 1) * 32768,
                  VTS_OFF + ((ti + 1) & 1) * 8192);
            if (ti + 2 < NTILES) LOAD((ti + 2) * 64);
        }

        // ---- lane-local online softmax (base 2), defer-max THR=8, per set ----
#pragma unroll
        for (int set = 0; set < 2; ++set) {
            const int rowq = wv * 32 + set * 16 + nn;
            float m01 = fmaxf(fmaxf(sc[set][0][0], sc[set][0][1]), fmaxf(sc[set][0][2], sc[set][0][3]));
            float m23 = fmaxf(fmaxf(sc[set][1][0], sc[set][1][1]), fmaxf(sc[set][1][2], sc[set][1][3]));
            float m45 = fmaxf(fmaxf(sc[set][2][0], sc[set][2][1]), fmaxf(sc[set][2][2], sc[set][2][3]));
            float m67 = fmaxf(fmaxf(sc[set][3][0], sc[set][3][1]), fmaxf(sc[set][3][2], sc[set][3][3]));
            float tm = fmaxf(fmaxf(m01, m23), fmaxf(m45, m67));
            tm = fmaxf(tm, __shfl_xor(tm, 16));
            tm = fmaxf(tm, __shfl_xor(tm, 32));   // all quads now hold row-max

            if (__any(tm > mrow[set] + 8.0f)) {   // wave-uniform rescale path
                float mnew  = fmaxf(mrow[set], tm);
                float alpha = __builtin_amdgcn_exp2f(mrow[set] - mnew);
                mrow[set] = mnew;
                lrow[set] *= alpha;
#pragma unroll
                for (int r = 0; r < 4; ++r) {
                    float ar = __shfl(alpha, quad * 4 + r, 64);
                    Oacc[set][0][r] *= ar; Oacc[set][1][r] *= ar;
                    Oacc[set][2][r] *= ar; Oacc[set][3][r] *= ar;
                }
            }

            float p[4][4];
#pragma unroll
            for (int kt2 = 0; kt2 < 4; ++kt2)
#pragma unroll
                for (int r = 0; r < 4; ++r)
                    p[kt2][r] = __builtin_amdgcn_exp2f(sc[set][kt2][r] - mrow[set]);

            float s0s = (p[0][0] + p[0][1]) + (p[0][2] + p[0][3]);
            float s1s = (p[1][0] + p[1][1]) + (p[1][2] + p[1][3]);
            float s2s = (p[2][0] + p[2][1]) + (p[2][2] + p[2][3]);
            float s3s = (p[3][0] + p[3][1]) + (p[3][2] + p[3][3]);
            float psum = (s0s + s1s) + (s2s + s3s);
            psum += __shfl_xor(psum, 16);
            psum += __shfl_xor(psum, 32);
            lrow[set] += psum;

            // ---- pack + write P (4 x ds_write_b64, bit3-fixed swizzle) ----
#pragma unroll
            for (int kt2 = 0; kt2 < 4; ++kt2) {
                H4U pk;
                pk.p[0] = __builtin_amdgcn_cvt_pkrtz(p[kt2][0], p[kt2][1]);
                pk.p[1] = __builtin_amdgcn_cvt_pkrtz(p[kt2][2], p[kt2][3]);
                int key0 = kt2 * 16 + quad * 4;    // keys key0..key0+3 share a chunk
                int ch = (key0 >> 3) ^ swq;
                *(f16x4*)&pss[rowq][ch * 8 + (key0 & 7)] = pk.h;
            }
        }

        // ---- PV (wave-local P round-trip; vf shared across sets) ----
        {
            const int pr0 = wv * 32 + nn;
            __builtin_amdgcn_s_setprio(1);
#pragma unroll
            for (int ks2 = 0; ks2 < 2; ++ks2) {
                f16x8 pf0 = *(const f16x8*)&pss[pr0     ][((quad + 4 * ks2) ^ swq) * 8];
                f16x8 pf1 = *(const f16x8*)&pss[pr0 + 16][((quad + 4 * ks2) ^ swq) * 8];
#pragma unroll
                for (int et = 0; et < 4; ++et) {
                    int e = et * 16 + nn;
                    f16x8 vf = *(const f16x8*)&vts[e][((quad + 4 * ks2) ^ (e & 7)) * 8];
                    Oacc[0][et] = __builtin_amdgcn_mfma_f32_16x16x32_f16(pf0, vf, Oacc[0][et], 0, 0, 0);
                    Oacc[1][et] = __builtin_amdgcn_mfma_f32_16x16x32_f16(pf1, vf, Oacc[1][et], 0, 0, 0);
                }
            }
            __builtin_amdgcn_s_setprio(0);
        }
        __syncthreads();   // build(ti+1) visible + all buf reads done
    }

    // ---- epilogue ----
    float* ob = out + ((size_t)((b * L_ + l0) * H_ + h)) * E_;
#pragma unroll
    for (int set = 0; set < 2; ++set)
#pragma unroll
        for (int r = 0; r < 4; ++r) {
            float lr = __shfl(lrow[set], quad * 4 + r, 64);
            float inv = 1.0f / lr;
            int row = wv * 32 + set * 16 + quad * 4 + r;   // 0..255
#pragma unroll
            for (int et = 0; et < 4; ++et)
                ob[(size_t)row * (H_ * E_) + et * 16 + nn] = Oacc[set][et][r] * inv;
        }
}

extern "C" void kernel_launch(void* const* d_in, const int* in_sizes, int n_in,
                              void* d_out, int out_size, void* d_ws, size_t ws_size,
                              hipStream_t stream) {
    const float* qp = (const float*)d_in[0];
    const float* kp = (const float*)d_in[1];
    const float* vp = (const float*)d_in[2];
    const float* qo = (const float*)d_in[3];
    const float* qt = (const float*)d_in[4];
    const float* ko = (const float*)d_in[5];
    const float* kt = (const float*)d_in[6];
    float* out = (float*)d_out;

    qattn8<<<dim3(B_ * H_ * (L_ / QBLK)), dim3(NTH), 0, stream>>>(
        qp, kp, vp, qo, qt, ko, kt, out);
}